// Round 8
// baseline (519.530 us; speedup 1.0000x reference)
//
#include <hip/hip_runtime.h>
#include <hip/hip_bf16.h>
#include <stdint.h>

#define NN 100000
#define NE 1600000
#define IND 512
#define HID 128
#define OUTD 64
#define BN_EPS 1e-5f
#define NP 98        // ceil(NN/1024) dst partitions
#define PSZ 1024     // nodes per partition
#define PCAP 20480   // staging capacity per partition (mean 16384, +32 sigma)
#define BINCH 8192   // edges per k_bin block

typedef __attribute__((ext_vector_type(8))) short short8v;
typedef __attribute__((ext_vector_type(4))) float f32x4;

// ---- fp32 -> bf16 (RNE) ----------------------------------------------------
__device__ __forceinline__ ushort f2bf(float f, float& back) {
  uint u = __float_as_uint(f);
  uint r = u + 0x7FFFu + ((u >> 16) & 1u);
  ushort h = (ushort)(r >> 16);
  back = __uint_as_float(((uint)h) << 16);
  return h;
}
__device__ __forceinline__ ushort f2bf_n(float f) {
  uint u = __float_as_uint(f);
  uint r = u + 0x7FFFu + ((u >> 16) & 1u);
  return (ushort)(r >> 16);
}
__device__ __forceinline__ float bf2f(ushort h) {
  return __uint_as_float(((uint)h) << 16);
}

// ---------------- edge dtype probe -----------------------------------------
__global__ void k_detect(const int* __restrict__ e, int* __restrict__ flag) {
  __shared__ int nz;
  if (threadIdx.x == 0) nz = 0;
  __syncthreads();
  int v = e[2 * threadIdx.x + 1];
  if (v != 0) atomicAdd(&nz, 1);
  __syncthreads();
  if (threadIdx.x == 0) *flag = (nz == 0) ? 1 : 0;  // 1 => int64
}

__device__ __forceinline__ int edge_at(const int* e32, int f, int i) {
  if (f) return (int)((const long long*)e32)[i];
  return e32[i];
}

// ---------------- W1^T split prep: Wt[n][k] hi/lo bf16 ----------------------
__global__ void k_prepW(const float* __restrict__ W1, ushort* __restrict__ Wth,
                        ushort* __restrict__ Wtl) {
  int i = blockIdx.x * 256 + threadIdx.x;  // over 128*512
  if (i >= HID * IND) return;
  int n = i >> 9, k = i & 511;
  float w = W1[(size_t)k * HID + n];
  float back;
  ushort h = f2bf(w, back);
  Wth[i] = h;
  Wtl[i] = f2bf_n(w - back);
}

// ---------------- GEMM1 via split-bf16 MFMA: h1b = bf16(x @ W1) -------------
// BM=64, BN=128(=HID), BK=32, 16 K-steps. 4 waves (2x2), wave tile 32x64.
// Pipelined A+B reg-prefetch into LDS (r5 structure, proven 1.6 TB/s) at
// grid 1563 (~6 blocks/CU; r7's 782 was the occupancy cap) + r6's exact
// LDS-staged flush (the only pattern measured at WRITE=25 MB).
__global__ __launch_bounds__(256) void k_gemm1m(const float* __restrict__ x,
                                                const ushort* __restrict__ Wth,
                                                const ushort* __restrict__ Wtl,
                                                ushort* __restrict__ h1b) {
  // union: staging sAh[64*40]=2560 + sBh[128*40]=5120 + sBl=5120 -> 12800 u16
  //        epilogue sOut[64*136]=8704 u16 (fits in the same 25.6 KB)
  __shared__ ushort smem[12800];
  ushort* sAh = smem;            // [64][40]
  ushort* sBh = smem + 2560;     // [128][40]
  ushort* sBl = smem + 7680;     // [128][40]
  ushort* sOut = smem;           // epilogue reuse
  const int tid = threadIdx.x;
  const int lane = tid & 63, wid = tid >> 6;
  const int wr = wid >> 1, wc = wid & 1;
  const int lrow = lane & 15, lkg = lane >> 4;
  const int row0 = blockIdx.x * 64;

  f32x4 acc[2][4];
#pragma unroll
  for (int m = 0; m < 2; ++m)
#pragma unroll
    for (int n = 0; n < 4; ++n) acc[m][n] = (f32x4){0.f, 0.f, 0.f, 0.f};

  float4 ra[2];
  uint4 rbh[2], rbl[2];

#pragma unroll
  for (int i = 0; i < 2; ++i) {
    int flat = i * 256 + tid, r = flat >> 3, kq = flat & 7;
    int grow = row0 + r; if (grow > NN - 1) grow = NN - 1;
    ra[i] = *(const float4*)(x + (size_t)grow * IND + kq * 4);
  }
#pragma unroll
  for (int i = 0; i < 2; ++i) {
    int flat = i * 256 + tid, col = flat >> 2, kc = flat & 3;
    rbh[i] = *(const uint4*)(Wth + (size_t)col * IND + kc * 8);
    rbl[i] = *(const uint4*)(Wtl + (size_t)col * IND + kc * 8);
  }

  for (int s = 0; s < 16; ++s) {
    __syncthreads();  // prior step's LDS reads complete
#pragma unroll
    for (int i = 0; i < 2; ++i) {
      int flat = i * 256 + tid, r = flat >> 3, kq = flat & 7;
      ushort4 hi;
      hi.x = f2bf_n(ra[i].x);
      hi.y = f2bf_n(ra[i].y);
      hi.z = f2bf_n(ra[i].z);
      hi.w = f2bf_n(ra[i].w);
      *(ushort4*)&sAh[r * 40 + kq * 4] = hi;
    }
#pragma unroll
    for (int i = 0; i < 2; ++i) {
      int flat = i * 256 + tid, col = flat >> 2, kc = flat & 3;
      *(uint4*)&sBh[col * 40 + kc * 8] = rbh[i];
      *(uint4*)&sBl[col * 40 + kc * 8] = rbl[i];
    }
    if (s < 15) {
      int kt = (s + 1) * 32;
#pragma unroll
      for (int i = 0; i < 2; ++i) {
        int flat = i * 256 + tid, r = flat >> 3, kq = flat & 7;
        int grow = row0 + r; if (grow > NN - 1) grow = NN - 1;
        ra[i] = *(const float4*)(x + (size_t)grow * IND + kt + kq * 4);
      }
#pragma unroll
      for (int i = 0; i < 2; ++i) {
        int flat = i * 256 + tid, col = flat >> 2, kc = flat & 3;
        rbh[i] = *(const uint4*)(Wth + (size_t)col * IND + kt + kc * 8);
        rbl[i] = *(const uint4*)(Wtl + (size_t)col * IND + kt + kc * 8);
      }
    }
    __syncthreads();  // LDS writes visible
    short8v ah[2], bh[4], bl[4];
#pragma unroll
    for (int m = 0; m < 2; ++m) {
      int r = wr * 32 + m * 16 + lrow;
      ah[m] = *(const short8v*)&sAh[r * 40 + lkg * 8];
    }
#pragma unroll
    for (int n = 0; n < 4; ++n) {
      int c = wc * 64 + n * 16 + lrow;
      bh[n] = *(const short8v*)&sBh[c * 40 + lkg * 8];
      bl[n] = *(const short8v*)&sBl[c * 40 + lkg * 8];
    }
#pragma unroll
    for (int m = 0; m < 2; ++m)
#pragma unroll
      for (int n = 0; n < 4; ++n) {
        acc[m][n] = __builtin_amdgcn_mfma_f32_16x16x32_bf16(ah[m], bh[n], acc[m][n], 0, 0, 0);
        acc[m][n] = __builtin_amdgcn_mfma_f32_16x16x32_bf16(ah[m], bl[n], acc[m][n], 0, 0, 0);
      }
  }

  // ---- epilogue: stage in LDS, then coalesced stores (r6's proven pattern)
  __syncthreads();  // last fragment reads done before overwriting smem
#pragma unroll
  for (int m = 0; m < 2; ++m)
#pragma unroll
    for (int i = 0; i < 4; ++i) {
      int lr = wr * 32 + m * 16 + lkg * 4 + i;
#pragma unroll
      for (int n = 0; n < 4; ++n)
        sOut[lr * 136 + wc * 64 + n * 16 + lrow] = f2bf_n(acc[m][n][i]);
    }
  __syncthreads();
  {
    int r = tid >> 2, ch = tid & 3;
    int grow = row0 + r;
    if (grow < NN) {
#pragma unroll
      for (int j = 0; j < 4; ++j)
        *(uint4*)(h1b + (size_t)grow * HID + ch * 32 + j * 8) =
            *(const uint4*)&sOut[r * 136 + ch * 32 + j * 8];
    }
  }
}

// ---------------- CSR build pass 1: partition binning -----------------------
__global__ __launch_bounds__(256) void k_bin(const int* __restrict__ edges,
                                             const int* __restrict__ flag,
                                             int* __restrict__ gCursor,
                                             int* __restrict__ staging) {
  __shared__ int cnt[NP], scn[NP], base[NP], cur[NP];
  __shared__ int items[BINCH];  // 32 KB
  const int tid = threadIdx.x;
  const int e0 = blockIdx.x * BINCH;
  const int ecnt = min(BINCH, NE - e0);
  const int f = *flag;
  for (int i = tid; i < NP; i += 256) cnt[i] = 0;
  __syncthreads();
  for (int i = tid; i < ecnt; i += 256) {
    int d = edge_at(edges, f, NE + e0 + i);
    atomicAdd(&cnt[d >> 10], 1);
  }
  __syncthreads();
  if (tid == 0) {
    int s = 0;
    for (int p = 0; p < NP; ++p) { scn[p] = s; s += cnt[p]; }
  }
  __syncthreads();
  if (tid < NP) {
    base[tid] = (cnt[tid] > 0) ? atomicAdd(&gCursor[tid], cnt[tid]) : 0;
    cur[tid] = 0;
  }
  __syncthreads();
  for (int i = tid; i < ecnt; i += 256) {
    int d = edge_at(edges, f, NE + e0 + i);
    int s = edge_at(edges, f, e0 + i);
    int p = d >> 10;
    int lp = atomicAdd(&cur[p], 1);
    items[scn[p] + lp] = (s << 10) | (d & (PSZ - 1));
  }
  __syncthreads();
  for (int p = 0; p < NP; ++p) {
    int c = cnt[p];
    if (c == 0) continue;
    int gb = base[p];
    int* dst = staging + (size_t)p * PCAP;
    for (int i = tid; i < c; i += 256) {
      int gpos = gb + i;
      if (gpos < PCAP) dst[gpos] = items[scn[p] + i];
    }
  }
}

// ---------------- CSR build pass 2a: scan partition totals ------------------
__global__ void k_partscan(const int* __restrict__ gCursor,
                           int* __restrict__ partBase, int* __restrict__ offsets) {
  __shared__ int s[128];
  int tid = threadIdx.x;
  int v = (tid < NP) ? min(gCursor[tid], PCAP) : 0;
  s[tid] = v;
  __syncthreads();
  for (int off = 1; off < 128; off <<= 1) {
    int t = (tid >= off) ? s[tid - off] : 0;
    __syncthreads();
    s[tid] += t;
    __syncthreads();
  }
  if (tid < NP) partBase[tid] = s[tid] - v;
  if (tid == 0) { partBase[NP] = NE; offsets[NN] = NE; }
}

// ---------------- CSR build pass 2b: per-partition counting sort ------------
__global__ __launch_bounds__(256) void k_csrpart(const int* __restrict__ staging,
                                                 const int* __restrict__ gCursor,
                                                 const int* __restrict__ partBase,
                                                 int* __restrict__ offsets,
                                                 int* __restrict__ csr_src) {
  __shared__ int cnt[PSZ];       // becomes exclusive scan
  __shared__ int cur[PSZ];
  __shared__ int tsum[256];
  __shared__ int srcbuf[PCAP];   // 80 KB
  const int tid = threadIdx.x;
  const int p = blockIdx.x;
  const int tot = min(gCursor[p], PCAP);
  const int gbase = partBase[p];
  const int* st = staging + (size_t)p * PCAP;
  for (int i = tid; i < PSZ; i += 256) { cnt[i] = 0; cur[i] = 0; }
  __syncthreads();
  for (int i = tid; i < tot; i += 256) atomicAdd(&cnt[st[i] & (PSZ - 1)], 1);
  __syncthreads();
  int b0 = tid * 4;
  int c0 = cnt[b0], c1 = cnt[b0 + 1], c2 = cnt[b0 + 2], c3 = cnt[b0 + 3];
  int ls = c0 + c1 + c2 + c3;
  tsum[tid] = ls;
  __syncthreads();
  for (int off = 1; off < 256; off <<= 1) {
    int t = (tid >= off) ? tsum[tid - off] : 0;
    __syncthreads();
    tsum[tid] += t;
    __syncthreads();
  }
  int ebase = tsum[tid] - ls;
  cnt[b0] = ebase;
  cnt[b0 + 1] = ebase + c0;
  cnt[b0 + 2] = ebase + c0 + c1;
  cnt[b0 + 3] = ebase + c0 + c1 + c2;
  __syncthreads();
  for (int i = tid; i < PSZ; i += 256) {
    int node = p * PSZ + i;
    if (node < NN) offsets[node] = gbase + cnt[i];
  }
  for (int i = tid; i < tot; i += 256) {
    int item = st[i];
    int dl = item & (PSZ - 1);
    int lp = atomicAdd(&cur[dl], 1);
    srcbuf[cnt[dl] + lp] = item >> 10;
  }
  __syncthreads();
  for (int i = tid; i < tot; i += 256) csr_src[gbase + i] = srcbuf[i];
}

// ---------------- Aggregation 1 (+b1): aggb[n] = bf16(sum h1[src] + b1) ----
__global__ __launch_bounds__(256) void k_agg1(const ushort* __restrict__ h1b,
                                              const int* __restrict__ offsets,
                                              const int* __restrict__ csr_src,
                                              const float* __restrict__ b1,
                                              ushort* __restrict__ aggb) {
  int w = threadIdx.x >> 6, lane = threadIdx.x & 63;
  int n = blockIdx.x * 4 + w;
  if (n >= NN) return;
  int beg = offsets[n], end = offsets[n + 1];
  const uint* h = (const uint*)h1b;
  float2 acc = ((const float2*)b1)[lane];
  int i = beg;
  for (; i + 1 < end; i += 2) {
    uint v0 = h[(size_t)csr_src[i] * 64 + lane];
    uint v1 = h[(size_t)csr_src[i + 1] * 64 + lane];
    acc.x += __uint_as_float(v0 << 16) + __uint_as_float(v1 << 16);
    acc.y += __uint_as_float(v0 & 0xffff0000u) + __uint_as_float(v1 & 0xffff0000u);
  }
  if (i < end) {
    uint v = h[(size_t)csr_src[i] * 64 + lane];
    acc.x += __uint_as_float(v << 16);
    acc.y += __uint_as_float(v & 0xffff0000u);
  }
  uint o = (uint)f2bf_n(acc.x) | ((uint)f2bf_n(acc.y) << 16);
  ((uint*)aggb)[(size_t)n * 64 + lane] = o;
}

// ---------------- BN stats (bf16 input) ------------------------------------
__global__ __launch_bounds__(256) void k_bnstats(const ushort* __restrict__ aggb,
                                                 float* __restrict__ gsum,
                                                 float* __restrict__ gsq) {
  __shared__ float2 ss[4][64], qq[4][64];
  int tid = threadIdx.x;
  int lane = tid & 63, g = tid >> 6;
  int r0 = blockIdx.x * 128;
  const uint* a = (const uint*)aggb;
  float2 s = {0.f, 0.f}, q = {0.f, 0.f};
  for (int k = 0; k < 32; ++k) {
    int r = r0 + g + 4 * k;
    if (r < NN) {
      uint v = a[(size_t)r * 64 + lane];
      float lo = __uint_as_float(v << 16);
      float hi = __uint_as_float(v & 0xffff0000u);
      s.x += lo; s.y += hi;
      q.x += lo * lo; q.y += hi * hi;
    }
  }
  ss[g][lane] = s; qq[g][lane] = q;
  __syncthreads();
  if (g == 0) {
    float2 S = ss[0][lane], Q = qq[0][lane];
#pragma unroll
    for (int gg = 1; gg < 4; ++gg) {
      S.x += ss[gg][lane].x; S.y += ss[gg][lane].y;
      Q.x += qq[gg][lane].x; Q.y += qq[gg][lane].y;
    }
    atomicAdd(&gsum[2 * lane], S.x);
    atomicAdd(&gsum[2 * lane + 1], S.y);
    atomicAdd(&gsq[2 * lane], Q.x);
    atomicAdd(&gsq[2 * lane + 1], Q.y);
  }
}

__global__ void k_bnfin(const float* __restrict__ gsum, const float* __restrict__ gsq,
                        const float* __restrict__ gamma, const float* __restrict__ beta,
                        float* __restrict__ isg, float* __restrict__ bb) {
  int c = threadIdx.x;  // 128 threads
  float mean = gsum[c] * (1.f / NN);
  float var = gsq[c] * (1.f / NN) - mean * mean;
  var = fmaxf(var, 0.f);
  float inv = 1.f / sqrtf(var + BN_EPS);
  float g = gamma[c] * inv;
  isg[c] = g;
  bb[c] = beta[c] - mean * g;
}

// ---------------- GEMM2 (BN+ReLU fused, bf16 A): h2b = bf16(relu(bn(aggb))@W2)
__global__ __launch_bounds__(256) void k_gemm2(const ushort* __restrict__ aggb,
                                               const float* __restrict__ W2,
                                               const float* __restrict__ isg,
                                               const float* __restrict__ bb,
                                               ushort* __restrict__ h2b) {
  __shared__ float As[32][132];
  __shared__ float Bs[32][68];
  __shared__ float isgS[128], bbS[128];
  const int tid = threadIdx.x;
  if (tid < 128) { isgS[tid] = isg[tid]; bbS[tid] = bb[tid]; }
  __syncthreads();
  const int tr = tid >> 4, tc = tid & 15;
  const int row0 = blockIdx.x * 128;
  float acc[8][4];
#pragma unroll
  for (int i = 0; i < 8; ++i)
#pragma unroll
    for (int j = 0; j < 4; ++j) acc[i][j] = 0.f;

  for (int kt = 0; kt < HID; kt += 32) {
#pragma unroll
    for (int rr = 0; rr < 4; ++rr) {
      int idx = tid + rr * 256;
      int r = idx >> 3;
      int c = (idx & 7) << 2;
      int row = row0 + r; if (row > NN - 1) row = NN - 1;
      ushort4 v4 = *(const ushort4*)(aggb + (size_t)row * HID + kt + c);
      int k0 = kt + c;
      float vx = fmaxf(fmaf(bf2f(v4.x), isgS[k0 + 0], bbS[k0 + 0]), 0.f);
      float vy = fmaxf(fmaf(bf2f(v4.y), isgS[k0 + 1], bbS[k0 + 1]), 0.f);
      float vz = fmaxf(fmaf(bf2f(v4.z), isgS[k0 + 2], bbS[k0 + 2]), 0.f);
      float vw = fmaxf(fmaf(bf2f(v4.w), isgS[k0 + 3], bbS[k0 + 3]), 0.f);
      As[c + 0][r] = vx; As[c + 1][r] = vy;
      As[c + 2][r] = vz; As[c + 3][r] = vw;
    }
#pragma unroll
    for (int rr = 0; rr < 2; ++rr) {
      int idx = tid + rr * 256;
      int kk = idx >> 4;
      int cc = (idx & 15) << 2;
      *(float4*)&Bs[kk][cc] = *(const float4*)(W2 + (size_t)(kt + kk) * OUTD + cc);
    }
    __syncthreads();
#pragma unroll
    for (int kk = 0; kk < 32; ++kk) {
      float a[8], b[4];
      *(float4*)&a[0] = *(const float4*)&As[kk][tr * 8];
      *(float4*)&a[4] = *(const float4*)&As[kk][tr * 8 + 4];
      *(float4*)&b[0] = *(const float4*)&Bs[kk][tc * 4];
#pragma unroll
      for (int i = 0; i < 8; ++i)
#pragma unroll
        for (int j = 0; j < 4; ++j) acc[i][j] = fmaf(a[i], b[j], acc[i][j]);
    }
    __syncthreads();
  }
#pragma unroll
  for (int i = 0; i < 8; ++i) {
    int row = row0 + tr * 8 + i;
    if (row < NN) {
      ushort4 o;
      o.x = f2bf_n(acc[i][0]); o.y = f2bf_n(acc[i][1]);
      o.z = f2bf_n(acc[i][2]); o.w = f2bf_n(acc[i][3]);
      *(ushort4*)(h2b + (size_t)row * OUTD + tc * 4) = o;
    }
  }
}

// ---------------- Aggregation 2 + b2 + L2 normalize + fp32 store -----------
__global__ __launch_bounds__(256) void k_agg2norm(const ushort* __restrict__ h2b,
                                                  const int* __restrict__ offsets,
                                                  const int* __restrict__ csr_src,
                                                  const float* __restrict__ b2,
                                                  float* __restrict__ out) {
  int w = threadIdx.x >> 6, lane = threadIdx.x & 63;
  int n = blockIdx.x * 4 + w;
  if (n >= NN) return;
  int beg = offsets[n], end = offsets[n + 1];
  float acc = b2[lane];
  int i = beg;
  for (; i + 1 < end; i += 2) {
    acc += bf2f(h2b[(size_t)csr_src[i] * OUTD + lane]) +
           bf2f(h2b[(size_t)csr_src[i + 1] * OUTD + lane]);
  }
  if (i < end) acc += bf2f(h2b[(size_t)csr_src[i] * OUTD + lane]);
  float q = acc * acc;
#pragma unroll
  for (int off = 32; off > 0; off >>= 1) q += __shfl_xor(q, off);
  float norm = sqrtf(q);
  float scale = 1.f / fmaxf(norm, 1e-12f);
  out[(size_t)n * OUTD + lane] = acc * scale;
}

// ---------------- launch ----------------------------------------------------
extern "C" void kernel_launch(void* const* d_in, const int* in_sizes, int n_in,
                              void* d_out, int out_size, void* d_ws, size_t ws_size,
                              hipStream_t stream) {
  const float* x     = (const float*)d_in[0];
  const int*   edges = (const int*)d_in[1];
  const float* W1    = (const float*)d_in[2];
  const float* b1    = (const float*)d_in[3];
  const float* W2    = (const float*)d_in[4];
  const float* b2    = (const float*)d_in[5];
  const float* gamma = (const float*)d_in[6];
  const float* beta  = (const float*)d_in[7];

  char* ws = (char*)d_ws;
  ushort* h1b     = (ushort*)(ws);                // 25.6 MB
  ushort* aggb    = (ushort*)(ws + 26000000);     // 25.6 MB (bf16 now)
  int*    csr_src = (int*)(ws + 77500000);        // 6.4 MB
  int*    offsets = (int*)(ws + 84000000);        // 100001 ints
  int*    staging = (int*)(ws + 84400128);        // 98*20480*4 = 8,028,160 B
  int*    gCursor = (int*)(ws + 92428544);        // 98 ints (512B region)
  int*    partBase= (int*)(ws + 92429056);        // 99 ints (512B region)
  float*  gsum    = (float*)(ws + 92429568);      // 128 f
  float*  gsq     = (float*)(ws + 92430080);      // 128 f
  float*  isg     = (float*)(ws + 92430592);      // 128 f
  float*  bbv     = (float*)(ws + 92431104);      // 128 f
  int*    eflag   = (int*)(ws + 92431616);        // 1 int
  ushort* Wth     = (ushort*)(ws + 92432128);     // 128 KB
  ushort* Wtl     = (ushort*)(ws + 92563200);     // 128 KB
  ushort* h2b     = h1b;                          // reuse (h1b dead after agg1)

  if (ws_size < 92700000) return;  // scratch layout requirement

  // zero gCursor + partBase + gsum + gsq (2 KB)
  hipMemsetAsync(gCursor, 0, 2048, stream);

  k_detect<<<1, 64, 0, stream>>>(edges, eflag);
  k_prepW<<<256, 256, 0, stream>>>(W1, Wth, Wtl);
  k_gemm1m<<<1563, 256, 0, stream>>>(x, Wth, Wtl, h1b);
  k_bin<<<196, 256, 0, stream>>>(edges, eflag, gCursor, staging);
  k_partscan<<<1, 128, 0, stream>>>(gCursor, partBase, offsets);
  k_csrpart<<<NP, 256, 0, stream>>>(staging, gCursor, partBase, offsets, csr_src);
  k_agg1<<<25000, 256, 0, stream>>>(h1b, offsets, csr_src, b1, aggb);
  k_bnstats<<<782, 256, 0, stream>>>(aggb, gsum, gsq);
  k_bnfin<<<1, 128, 0, stream>>>(gsum, gsq, gamma, beta, isg, bbv);
  k_gemm2<<<782, 256, 0, stream>>>(aggb, W2, isg, bbv, h2b);
  k_agg2norm<<<25000, 256, 0, stream>>>(h2b, offsets, csr_src, b2,
                                        (float*)d_out);
}

// Round 9
// 464.360 us; speedup vs baseline: 1.1188x; 1.1188x over previous
//
#include <hip/hip_runtime.h>
#include <hip/hip_bf16.h>
#include <stdint.h>

#define NN 100000
#define NE 1600000
#define IND 512
#define HID 128
#define OUTD 64
#define BN_EPS 1e-5f
#define NP 98        // ceil(NN/1024) dst partitions
#define PSZ 1024     // nodes per partition
#define PCAP 20480   // staging capacity per partition (mean 16384, +32 sigma)
#define BINCH 8192   // edges per k_bin block

typedef __attribute__((ext_vector_type(8))) short short8v;
typedef __attribute__((ext_vector_type(4))) float f32x4;

// ---- fp32 -> bf16 (RNE) ----------------------------------------------------
__device__ __forceinline__ ushort f2bf(float f, float& back) {
  uint u = __float_as_uint(f);
  uint r = u + 0x7FFFu + ((u >> 16) & 1u);
  ushort h = (ushort)(r >> 16);
  back = __uint_as_float(((uint)h) << 16);
  return h;
}
__device__ __forceinline__ ushort f2bf_n(float f) {
  uint u = __float_as_uint(f);
  uint r = u + 0x7FFFu + ((u >> 16) & 1u);
  return (ushort)(r >> 16);
}
__device__ __forceinline__ float bf2f(ushort h) {
  return __uint_as_float(((uint)h) << 16);
}

// ---------------- edge dtype probe -----------------------------------------
__global__ void k_detect(const int* __restrict__ e, int* __restrict__ flag) {
  __shared__ int nz;
  if (threadIdx.x == 0) nz = 0;
  __syncthreads();
  int v = e[2 * threadIdx.x + 1];
  if (v != 0) atomicAdd(&nz, 1);
  __syncthreads();
  if (threadIdx.x == 0) *flag = (nz == 0) ? 1 : 0;  // 1 => int64
}

__device__ __forceinline__ int edge_at(const int* e32, int f, int i) {
  if (f) return (int)((const long long*)e32)[i];
  return e32[i];
}

// ---------------- W1^T split prep: Wt[n][k] hi/lo bf16 ----------------------
__global__ void k_prepW(const float* __restrict__ W1, ushort* __restrict__ Wth,
                        ushort* __restrict__ Wtl) {
  int i = blockIdx.x * 256 + threadIdx.x;  // over 128*512
  if (i >= HID * IND) return;
  int n = i >> 9, k = i & 511;
  float w = W1[(size_t)k * HID + n];
  float back;
  ushort h = f2bf(w, back);
  Wth[i] = h;
  Wtl[i] = f2bf_n(w - back);
}

// ---------------- GEMM1 via split-bf16 MFMA: h1b = bf16(x @ W1) -------------
// BM=128, BN=128(=HID), BK=32, 16 K-steps. 4 waves (2x2), wave tile 64x64.
// r7 pipelined K-loop (proven 1.5-1.6 TB/s) + INSTRUCTION-LINEAR epilogue:
// each store instruction's 64 lanes cover 1KB contiguous (16 full 64B lines)
// -- does not rely on cross-instruction write combining (which failed in
// r5/r7/r8: WRITE 84/87/123 MB for 25.6 MB payload).
__global__ __launch_bounds__(256) void k_gemm1m(const float* __restrict__ x,
                                                const ushort* __restrict__ Wth,
                                                const ushort* __restrict__ Wtl,
                                                ushort* __restrict__ h1b) {
  // union: staging sAh[128*40]+sBh[128*40]+sBl[128*40] = 15360 u16
  //        epilogue sOut[128][136] = 17408 u16 (34,816 B)
  __shared__ ushort smem[17408];
  ushort* sAh = smem;            // [128][40]
  ushort* sBh = smem + 5120;     // [128][40]
  ushort* sBl = smem + 10240;    // [128][40]
  ushort* sOut = smem;           // epilogue reuse, pitch 136 (16B-aligned rows)
  const int tid = threadIdx.x;
  const int lane = tid & 63, wid = tid >> 6;
  const int wr = wid >> 1, wc = wid & 1;
  const int lrow = lane & 15, lkg = lane >> 4;
  const int row0 = blockIdx.x * 128;

  f32x4 acc[4][4];
#pragma unroll
  for (int m = 0; m < 4; ++m)
#pragma unroll
    for (int n = 0; n < 4; ++n) acc[m][n] = (f32x4){0.f, 0.f, 0.f, 0.f};

  float4 ra[4];
  uint4 rbh[2], rbl[2];

#pragma unroll
  for (int i = 0; i < 4; ++i) {
    int flat = i * 256 + tid, r = flat >> 3, kq = flat & 7;
    int grow = row0 + r; if (grow > NN - 1) grow = NN - 1;
    ra[i] = *(const float4*)(x + (size_t)grow * IND + kq * 4);
  }
#pragma unroll
  for (int i = 0; i < 2; ++i) {
    int flat = i * 256 + tid, col = flat >> 2, kc = flat & 3;
    rbh[i] = *(const uint4*)(Wth + (size_t)col * IND + kc * 8);
    rbl[i] = *(const uint4*)(Wtl + (size_t)col * IND + kc * 8);
  }

  for (int s = 0; s < 16; ++s) {
    __syncthreads();  // prior step's LDS reads complete
#pragma unroll
    for (int i = 0; i < 4; ++i) {
      int flat = i * 256 + tid, r = flat >> 3, kq = flat & 7;
      ushort4 hi;
      hi.x = f2bf_n(ra[i].x);
      hi.y = f2bf_n(ra[i].y);
      hi.z = f2bf_n(ra[i].z);
      hi.w = f2bf_n(ra[i].w);
      *(ushort4*)&sAh[r * 40 + kq * 4] = hi;
    }
#pragma unroll
    for (int i = 0; i < 2; ++i) {
      int flat = i * 256 + tid, col = flat >> 2, kc = flat & 3;
      *(uint4*)&sBh[col * 40 + kc * 8] = rbh[i];
      *(uint4*)&sBl[col * 40 + kc * 8] = rbl[i];
    }
    if (s < 15) {
      int kt = (s + 1) * 32;
#pragma unroll
      for (int i = 0; i < 4; ++i) {
        int flat = i * 256 + tid, r = flat >> 3, kq = flat & 7;
        int grow = row0 + r; if (grow > NN - 1) grow = NN - 1;
        ra[i] = *(const float4*)(x + (size_t)grow * IND + kt + kq * 4);
      }
#pragma unroll
      for (int i = 0; i < 2; ++i) {
        int flat = i * 256 + tid, col = flat >> 2, kc = flat & 3;
        rbh[i] = *(const uint4*)(Wth + (size_t)col * IND + kt + kc * 8);
        rbl[i] = *(const uint4*)(Wtl + (size_t)col * IND + kt + kc * 8);
      }
    }
    __syncthreads();  // LDS writes visible
    short8v ah[4], bh[4], bl[4];
#pragma unroll
    for (int m = 0; m < 4; ++m) {
      int r = wr * 64 + m * 16 + lrow;
      ah[m] = *(const short8v*)&sAh[r * 40 + lkg * 8];
    }
#pragma unroll
    for (int n = 0; n < 4; ++n) {
      int c = wc * 64 + n * 16 + lrow;
      bh[n] = *(const short8v*)&sBh[c * 40 + lkg * 8];
      bl[n] = *(const short8v*)&sBl[c * 40 + lkg * 8];
    }
#pragma unroll
    for (int m = 0; m < 4; ++m)
#pragma unroll
      for (int n = 0; n < 4; ++n) {
        acc[m][n] = __builtin_amdgcn_mfma_f32_16x16x32_bf16(ah[m], bh[n], acc[m][n], 0, 0, 0);
        acc[m][n] = __builtin_amdgcn_mfma_f32_16x16x32_bf16(ah[m], bl[n], acc[m][n], 0, 0, 0);
      }
  }

  // ---- epilogue: stage in LDS, flush with instruction-linear stores
  __syncthreads();  // last fragment reads done before overwriting smem
#pragma unroll
  for (int m = 0; m < 4; ++m)
#pragma unroll
    for (int i = 0; i < 4; ++i) {
      int lr = wr * 64 + m * 16 + lkg * 4 + i;
#pragma unroll
      for (int n = 0; n < 4; ++n)
        sOut[lr * 136 + wc * 64 + n * 16 + lrow] = f2bf_n(acc[m][n][i]);
    }
  __syncthreads();
#pragma unroll
  for (int j = 0; j < 8; ++j) {
    int flat = j * 256 + tid;        // 2048 chunks of 16B: 128 rows x 16
    int r = flat >> 4, c = flat & 15;
    int grow = row0 + r;
    if (grow < NN)
      *(uint4*)(h1b + (size_t)grow * HID + c * 8) =
          *(const uint4*)&sOut[r * 136 + c * 8];
  }
}

// ---------------- CSR build pass 1: partition binning -----------------------
__global__ __launch_bounds__(256) void k_bin(const int* __restrict__ edges,
                                             const int* __restrict__ flag,
                                             int* __restrict__ gCursor,
                                             int* __restrict__ staging) {
  __shared__ int cnt[NP], scn[NP], base[NP], cur[NP];
  __shared__ int items[BINCH];  // 32 KB
  const int tid = threadIdx.x;
  const int e0 = blockIdx.x * BINCH;
  const int ecnt = min(BINCH, NE - e0);
  const int f = *flag;
  for (int i = tid; i < NP; i += 256) cnt[i] = 0;
  __syncthreads();
  for (int i = tid; i < ecnt; i += 256) {
    int d = edge_at(edges, f, NE + e0 + i);
    atomicAdd(&cnt[d >> 10], 1);
  }
  __syncthreads();
  if (tid == 0) {
    int s = 0;
    for (int p = 0; p < NP; ++p) { scn[p] = s; s += cnt[p]; }
  }
  __syncthreads();
  if (tid < NP) {
    base[tid] = (cnt[tid] > 0) ? atomicAdd(&gCursor[tid], cnt[tid]) : 0;
    cur[tid] = 0;
  }
  __syncthreads();
  for (int i = tid; i < ecnt; i += 256) {
    int d = edge_at(edges, f, NE + e0 + i);
    int s = edge_at(edges, f, e0 + i);
    int p = d >> 10;
    int lp = atomicAdd(&cur[p], 1);
    items[scn[p] + lp] = (s << 10) | (d & (PSZ - 1));
  }
  __syncthreads();
  for (int p = 0; p < NP; ++p) {
    int c = cnt[p];
    if (c == 0) continue;
    int gb = base[p];
    int* dst = staging + (size_t)p * PCAP;
    for (int i = tid; i < c; i += 256) {
      int gpos = gb + i;
      if (gpos < PCAP) dst[gpos] = items[scn[p] + i];
    }
  }
}

// ---------------- CSR build pass 2a: scan partition totals ------------------
__global__ void k_partscan(const int* __restrict__ gCursor,
                           int* __restrict__ partBase, int* __restrict__ offsets) {
  __shared__ int s[128];
  int tid = threadIdx.x;
  int v = (tid < NP) ? min(gCursor[tid], PCAP) : 0;
  s[tid] = v;
  __syncthreads();
  for (int off = 1; off < 128; off <<= 1) {
    int t = (tid >= off) ? s[tid - off] : 0;
    __syncthreads();
    s[tid] += t;
    __syncthreads();
  }
  if (tid < NP) partBase[tid] = s[tid] - v;
  if (tid == 0) { partBase[NP] = NE; offsets[NN] = NE; }
}

// ---------------- CSR build pass 2b: per-partition counting sort ------------
__global__ __launch_bounds__(256) void k_csrpart(const int* __restrict__ staging,
                                                 const int* __restrict__ gCursor,
                                                 const int* __restrict__ partBase,
                                                 int* __restrict__ offsets,
                                                 int* __restrict__ csr_src) {
  __shared__ int cnt[PSZ];       // becomes exclusive scan
  __shared__ int cur[PSZ];
  __shared__ int tsum[256];
  __shared__ int srcbuf[PCAP];   // 80 KB
  const int tid = threadIdx.x;
  const int p = blockIdx.x;
  const int tot = min(gCursor[p], PCAP);
  const int gbase = partBase[p];
  const int* st = staging + (size_t)p * PCAP;
  for (int i = tid; i < PSZ; i += 256) { cnt[i] = 0; cur[i] = 0; }
  __syncthreads();
  for (int i = tid; i < tot; i += 256) atomicAdd(&cnt[st[i] & (PSZ - 1)], 1);
  __syncthreads();
  int b0 = tid * 4;
  int c0 = cnt[b0], c1 = cnt[b0 + 1], c2 = cnt[b0 + 2], c3 = cnt[b0 + 3];
  int ls = c0 + c1 + c2 + c3;
  tsum[tid] = ls;
  __syncthreads();
  for (int off = 1; off < 256; off <<= 1) {
    int t = (tid >= off) ? tsum[tid - off] : 0;
    __syncthreads();
    tsum[tid] += t;
    __syncthreads();
  }
  int ebase = tsum[tid] - ls;
  cnt[b0] = ebase;
  cnt[b0 + 1] = ebase + c0;
  cnt[b0 + 2] = ebase + c0 + c1;
  cnt[b0 + 3] = ebase + c0 + c1 + c2;
  __syncthreads();
  for (int i = tid; i < PSZ; i += 256) {
    int node = p * PSZ + i;
    if (node < NN) offsets[node] = gbase + cnt[i];
  }
  for (int i = tid; i < tot; i += 256) {
    int item = st[i];
    int dl = item & (PSZ - 1);
    int lp = atomicAdd(&cur[dl], 1);
    srcbuf[cnt[dl] + lp] = item >> 10;
  }
  __syncthreads();
  for (int i = tid; i < tot; i += 256) csr_src[gbase + i] = srcbuf[i];
}

// ---------------- Aggregation 1 (+b1): aggb[n] = bf16(sum h1[src] + b1) ----
__global__ __launch_bounds__(256) void k_agg1(const ushort* __restrict__ h1b,
                                              const int* __restrict__ offsets,
                                              const int* __restrict__ csr_src,
                                              const float* __restrict__ b1,
                                              ushort* __restrict__ aggb) {
  int w = threadIdx.x >> 6, lane = threadIdx.x & 63;
  int n = blockIdx.x * 4 + w;
  if (n >= NN) return;
  int beg = offsets[n], end = offsets[n + 1];
  const uint* h = (const uint*)h1b;
  float2 acc = ((const float2*)b1)[lane];
  int i = beg;
  for (; i + 1 < end; i += 2) {
    uint v0 = h[(size_t)csr_src[i] * 64 + lane];
    uint v1 = h[(size_t)csr_src[i + 1] * 64 + lane];
    acc.x += __uint_as_float(v0 << 16) + __uint_as_float(v1 << 16);
    acc.y += __uint_as_float(v0 & 0xffff0000u) + __uint_as_float(v1 & 0xffff0000u);
  }
  if (i < end) {
    uint v = h[(size_t)csr_src[i] * 64 + lane];
    acc.x += __uint_as_float(v << 16);
    acc.y += __uint_as_float(v & 0xffff0000u);
  }
  uint o = (uint)f2bf_n(acc.x) | ((uint)f2bf_n(acc.y) << 16);
  ((uint*)aggb)[(size_t)n * 64 + lane] = o;
}

// ---------------- BN stats (bf16 input) ------------------------------------
__global__ __launch_bounds__(256) void k_bnstats(const ushort* __restrict__ aggb,
                                                 float* __restrict__ gsum,
                                                 float* __restrict__ gsq) {
  __shared__ float2 ss[4][64], qq[4][64];
  int tid = threadIdx.x;
  int lane = tid & 63, g = tid >> 6;
  int r0 = blockIdx.x * 128;
  const uint* a = (const uint*)aggb;
  float2 s = {0.f, 0.f}, q = {0.f, 0.f};
  for (int k = 0; k < 32; ++k) {
    int r = r0 + g + 4 * k;
    if (r < NN) {
      uint v = a[(size_t)r * 64 + lane];
      float lo = __uint_as_float(v << 16);
      float hi = __uint_as_float(v & 0xffff0000u);
      s.x += lo; s.y += hi;
      q.x += lo * lo; q.y += hi * hi;
    }
  }
  ss[g][lane] = s; qq[g][lane] = q;
  __syncthreads();
  if (g == 0) {
    float2 S = ss[0][lane], Q = qq[0][lane];
#pragma unroll
    for (int gg = 1; gg < 4; ++gg) {
      S.x += ss[gg][lane].x; S.y += ss[gg][lane].y;
      Q.x += qq[gg][lane].x; Q.y += qq[gg][lane].y;
    }
    atomicAdd(&gsum[2 * lane], S.x);
    atomicAdd(&gsum[2 * lane + 1], S.y);
    atomicAdd(&gsq[2 * lane], Q.x);
    atomicAdd(&gsq[2 * lane + 1], Q.y);
  }
}

__global__ void k_bnfin(const float* __restrict__ gsum, const float* __restrict__ gsq,
                        const float* __restrict__ gamma, const float* __restrict__ beta,
                        float* __restrict__ isg, float* __restrict__ bb) {
  int c = threadIdx.x;  // 128 threads
  float mean = gsum[c] * (1.f / NN);
  float var = gsq[c] * (1.f / NN) - mean * mean;
  var = fmaxf(var, 0.f);
  float inv = 1.f / sqrtf(var + BN_EPS);
  float g = gamma[c] * inv;
  isg[c] = g;
  bb[c] = beta[c] - mean * g;
}

// ---------------- GEMM2 (BN+ReLU fused, bf16 A): h2b = bf16(relu(bn(aggb))@W2)
__global__ __launch_bounds__(256) void k_gemm2(const ushort* __restrict__ aggb,
                                               const float* __restrict__ W2,
                                               const float* __restrict__ isg,
                                               const float* __restrict__ bb,
                                               ushort* __restrict__ h2b) {
  __shared__ float As[32][132];
  __shared__ float Bs[32][68];
  __shared__ float isgS[128], bbS[128];
  const int tid = threadIdx.x;
  if (tid < 128) { isgS[tid] = isg[tid]; bbS[tid] = bb[tid]; }
  __syncthreads();
  const int tr = tid >> 4, tc = tid & 15;
  const int row0 = blockIdx.x * 128;
  float acc[8][4];
#pragma unroll
  for (int i = 0; i < 8; ++i)
#pragma unroll
    for (int j = 0; j < 4; ++j) acc[i][j] = 0.f;

  for (int kt = 0; kt < HID; kt += 32) {
#pragma unroll
    for (int rr = 0; rr < 4; ++rr) {
      int idx = tid + rr * 256;
      int r = idx >> 3;
      int c = (idx & 7) << 2;
      int row = row0 + r; if (row > NN - 1) row = NN - 1;
      ushort4 v4 = *(const ushort4*)(aggb + (size_t)row * HID + kt + c);
      int k0 = kt + c;
      float vx = fmaxf(fmaf(bf2f(v4.x), isgS[k0 + 0], bbS[k0 + 0]), 0.f);
      float vy = fmaxf(fmaf(bf2f(v4.y), isgS[k0 + 1], bbS[k0 + 1]), 0.f);
      float vz = fmaxf(fmaf(bf2f(v4.z), isgS[k0 + 2], bbS[k0 + 2]), 0.f);
      float vw = fmaxf(fmaf(bf2f(v4.w), isgS[k0 + 3], bbS[k0 + 3]), 0.f);
      As[c + 0][r] = vx; As[c + 1][r] = vy;
      As[c + 2][r] = vz; As[c + 3][r] = vw;
    }
#pragma unroll
    for (int rr = 0; rr < 2; ++rr) {
      int idx = tid + rr * 256;
      int kk = idx >> 4;
      int cc = (idx & 15) << 2;
      *(float4*)&Bs[kk][cc] = *(const float4*)(W2 + (size_t)(kt + kk) * OUTD + cc);
    }
    __syncthreads();
#pragma unroll
    for (int kk = 0; kk < 32; ++kk) {
      float a[8], b[4];
      *(float4*)&a[0] = *(const float4*)&As[kk][tr * 8];
      *(float4*)&a[4] = *(const float4*)&As[kk][tr * 8 + 4];
      *(float4*)&b[0] = *(const float4*)&Bs[kk][tc * 4];
#pragma unroll
      for (int i = 0; i < 8; ++i)
#pragma unroll
        for (int j = 0; j < 4; ++j) acc[i][j] = fmaf(a[i], b[j], acc[i][j]);
    }
    __syncthreads();
  }
#pragma unroll
  for (int i = 0; i < 8; ++i) {
    int row = row0 + tr * 8 + i;
    if (row < NN) {
      ushort4 o;
      o.x = f2bf_n(acc[i][0]); o.y = f2bf_n(acc[i][1]);
      o.z = f2bf_n(acc[i][2]); o.w = f2bf_n(acc[i][3]);
      *(ushort4*)(h2b + (size_t)row * OUTD + tc * 4) = o;
    }
  }
}

// ---------------- Aggregation 2 + b2 + L2 normalize + fp32 store -----------
__global__ __launch_bounds__(256) void k_agg2norm(const ushort* __restrict__ h2b,
                                                  const int* __restrict__ offsets,
                                                  const int* __restrict__ csr_src,
                                                  const float* __restrict__ b2,
                                                  float* __restrict__ out) {
  int w = threadIdx.x >> 6, lane = threadIdx.x & 63;
  int n = blockIdx.x * 4 + w;
  if (n >= NN) return;
  int beg = offsets[n], end = offsets[n + 1];
  float acc = b2[lane];
  int i = beg;
  for (; i + 1 < end; i += 2) {
    acc += bf2f(h2b[(size_t)csr_src[i] * OUTD + lane]) +
           bf2f(h2b[(size_t)csr_src[i + 1] * OUTD + lane]);
  }
  if (i < end) acc += bf2f(h2b[(size_t)csr_src[i] * OUTD + lane]);
  float q = acc * acc;
#pragma unroll
  for (int off = 32; off > 0; off >>= 1) q += __shfl_xor(q, off);
  float norm = sqrtf(q);
  float scale = 1.f / fmaxf(norm, 1e-12f);
  out[(size_t)n * OUTD + lane] = acc * scale;
}

// ---------------- launch ----------------------------------------------------
extern "C" void kernel_launch(void* const* d_in, const int* in_sizes, int n_in,
                              void* d_out, int out_size, void* d_ws, size_t ws_size,
                              hipStream_t stream) {
  const float* x     = (const float*)d_in[0];
  const int*   edges = (const int*)d_in[1];
  const float* W1    = (const float*)d_in[2];
  const float* b1    = (const float*)d_in[3];
  const float* W2    = (const float*)d_in[4];
  const float* b2    = (const float*)d_in[5];
  const float* gamma = (const float*)d_in[6];
  const float* beta  = (const float*)d_in[7];

  char* ws = (char*)d_ws;
  ushort* h1b     = (ushort*)(ws);                // 25.6 MB
  ushort* aggb    = (ushort*)(ws + 26000000);     // 25.6 MB (bf16)
  int*    csr_src = (int*)(ws + 77500000);        // 6.4 MB
  int*    offsets = (int*)(ws + 84000000);        // 100001 ints
  int*    staging = (int*)(ws + 84400128);        // 98*20480*4 = 8,028,160 B
  int*    gCursor = (int*)(ws + 92428544);        // 98 ints (512B region)
  int*    partBase= (int*)(ws + 92429056);        // 99 ints (512B region)
  float*  gsum    = (float*)(ws + 92429568);      // 128 f
  float*  gsq     = (float*)(ws + 92430080);      // 128 f
  float*  isg     = (float*)(ws + 92430592);      // 128 f
  float*  bbv     = (float*)(ws + 92431104);      // 128 f
  int*    eflag   = (int*)(ws + 92431616);        // 1 int
  ushort* Wth     = (ushort*)(ws + 92432128);     // 128 KB
  ushort* Wtl     = (ushort*)(ws + 92563200);     // 128 KB
  ushort* h2b     = h1b;                          // reuse (h1b dead after agg1)

  if (ws_size < 92700000) return;  // scratch layout requirement

  // zero gCursor + partBase + gsum + gsq (2 KB)
  hipMemsetAsync(gCursor, 0, 2048, stream);

  k_detect<<<1, 64, 0, stream>>>(edges, eflag);
  k_prepW<<<256, 256, 0, stream>>>(W1, Wth, Wtl);
  k_gemm1m<<<782, 256, 0, stream>>>(x, Wth, Wtl, h1b);
  k_bin<<<196, 256, 0, stream>>>(edges, eflag, gCursor, staging);
  k_partscan<<<1, 128, 0, stream>>>(gCursor, partBase, offsets);
  k_csrpart<<<NP, 256, 0, stream>>>(staging, gCursor, partBase, offsets, csr_src);
  k_agg1<<<25000, 256, 0, stream>>>(h1b, offsets, csr_src, b1, aggb);
  k_bnstats<<<782, 256, 0, stream>>>(aggb, gsum, gsq);
  k_bnfin<<<1, 128, 0, stream>>>(gsum, gsq, gamma, beta, isg, bbv);
  k_gemm2<<<782, 256, 0, stream>>>(aggb, W2, isg, bbv, h2b);
  k_agg2norm<<<25000, 256, 0, stream>>>(h2b, offsets, csr_src, b2,
                                        (float*)d_out);
}

// Round 10
// 420.821 us; speedup vs baseline: 1.2346x; 1.1035x over previous
//
#include <hip/hip_runtime.h>
#include <hip/hip_bf16.h>
#include <stdint.h>

#define NN 100000
#define NE 1600000
#define IND 512
#define HID 128
#define OUTD 64
#define BN_EPS 1e-5f
#define NP 98        // ceil(NN/1024) dst partitions
#define PSZ 1024     // nodes per partition
#define PCAP 20480   // staging capacity per partition (mean 16384, +32 sigma)
#define BINCH 8192   // edges per k_bin block

typedef __attribute__((ext_vector_type(8))) short short8v;
typedef __attribute__((ext_vector_type(4))) float f32x4;

// ---- fp32 -> bf16 (RNE) ----------------------------------------------------
__device__ __forceinline__ ushort f2bf(float f, float& back) {
  uint u = __float_as_uint(f);
  uint r = u + 0x7FFFu + ((u >> 16) & 1u);
  ushort h = (ushort)(r >> 16);
  back = __uint_as_float(((uint)h) << 16);
  return h;
}
__device__ __forceinline__ ushort f2bf_n(float f) {
  uint u = __float_as_uint(f);
  uint r = u + 0x7FFFu + ((u >> 16) & 1u);
  return (ushort)(r >> 16);
}
__device__ __forceinline__ float bf2f(ushort h) {
  return __uint_as_float(((uint)h) << 16);
}

// ---------------- edge dtype probe -----------------------------------------
__global__ void k_detect(const int* __restrict__ e, int* __restrict__ flag) {
  __shared__ int nz;
  if (threadIdx.x == 0) nz = 0;
  __syncthreads();
  int v = e[2 * threadIdx.x + 1];
  if (v != 0) atomicAdd(&nz, 1);
  __syncthreads();
  if (threadIdx.x == 0) *flag = (nz == 0) ? 1 : 0;  // 1 => int64
}

__device__ __forceinline__ int edge_at(const int* e32, int f, int i) {
  if (f) return (int)((const long long*)e32)[i];
  return e32[i];
}

// ---------------- W1^T split prep: Wt[n][k] hi/lo bf16 ----------------------
__global__ void k_prepW(const float* __restrict__ W1, ushort* __restrict__ Wth,
                        ushort* __restrict__ Wtl) {
  int i = blockIdx.x * 256 + threadIdx.x;  // over 128*512
  if (i >= HID * IND) return;
  int n = i >> 9, k = i & 511;
  float w = W1[(size_t)k * HID + n];
  float back;
  ushort h = f2bf(w, back);
  Wth[i] = h;
  Wtl[i] = f2bf_n(w - back);
}

// ---------------- GEMM1 via split-bf16 MFMA: h1b = bf16(x @ W1) -------------
// BM=128, BN=128(=HID), BK=32, 16 K-steps, 4 waves (2x2), wave tile 64x64.
// DOUBLE-BUFFERED LDS, ONE barrier per K-step. Loads for step s+1 are issued
// AFTER the barrier (not before it) so the compiler's `s_waitcnt vmcnt(0)`
// barrier-drain doesn't serialize them; the 32 MFMAs + ds_reads cover the
// load latency, and the convert/ds_write at step end consumes the data.
// (r5/r7/r9 issued loads right before the barrier -> every K-step stalled a
// full memory round-trip: 122us with nothing saturated.)
__global__ __launch_bounds__(256) void k_gemm1m(const float* __restrict__ x,
                                                const ushort* __restrict__ Wth,
                                                const ushort* __restrict__ Wtl,
                                                ushort* __restrict__ h1b) {
  // two staging buffers of 15360 u16 (Ah[128][40] | Bh[128][40] | Bl[128][40])
  // epilogue sOut[128][136]=17408 u16 aliases the pair (30720 u16 total).
  __shared__ ushort smem[30720];
  ushort* sOut = smem;
  const int tid = threadIdx.x;
  const int lane = tid & 63, wid = tid >> 6;
  const int wr = wid >> 1, wc = wid & 1;
  const int lrow = lane & 15, lkg = lane >> 4;
  const int row0 = blockIdx.x * 128;

  f32x4 acc[4][4];
#pragma unroll
  for (int m = 0; m < 4; ++m)
#pragma unroll
    for (int n = 0; n < 4; ++n) acc[m][n] = (f32x4){0.f, 0.f, 0.f, 0.f};

  float4 ra[4];
  uint4 rbh[2], rbl[2];

  // ---- prologue: load tile 0 into regs, stage into buffer 0
#pragma unroll
  for (int i = 0; i < 4; ++i) {
    int flat = i * 256 + tid, r = flat >> 3, kq = flat & 7;
    int grow = row0 + r; if (grow > NN - 1) grow = NN - 1;
    ra[i] = *(const float4*)(x + (size_t)grow * IND + kq * 4);
  }
#pragma unroll
  for (int i = 0; i < 2; ++i) {
    int flat = i * 256 + tid, col = flat >> 2, kc = flat & 3;
    rbh[i] = *(const uint4*)(Wth + (size_t)col * IND + kc * 8);
    rbl[i] = *(const uint4*)(Wtl + (size_t)col * IND + kc * 8);
  }
  {
    ushort* dAh = smem;
    ushort* dBh = smem + 5120;
    ushort* dBl = smem + 10240;
#pragma unroll
    for (int i = 0; i < 4; ++i) {
      int flat = i * 256 + tid, r = flat >> 3, kq = flat & 7;
      ushort4 hi;
      hi.x = f2bf_n(ra[i].x); hi.y = f2bf_n(ra[i].y);
      hi.z = f2bf_n(ra[i].z); hi.w = f2bf_n(ra[i].w);
      *(ushort4*)&dAh[r * 40 + kq * 4] = hi;
    }
#pragma unroll
    for (int i = 0; i < 2; ++i) {
      int flat = i * 256 + tid, col = flat >> 2, kc = flat & 3;
      *(uint4*)&dBh[col * 40 + kc * 8] = rbh[i];
      *(uint4*)&dBl[col * 40 + kc * 8] = rbl[i];
    }
  }

  int cur = 0;
  for (int s = 0; s < 16; ++s) {
    __syncthreads();  // buf[cur] writes visible (only barrier this step)
    // ---- issue next tile's global loads NOW (after the barrier drain):
    //      MFMA phase below hides their latency.
    if (s < 15) {
      int kt = (s + 1) * 32;
#pragma unroll
      for (int i = 0; i < 4; ++i) {
        int flat = i * 256 + tid, r = flat >> 3, kq = flat & 7;
        int grow = row0 + r; if (grow > NN - 1) grow = NN - 1;
        ra[i] = *(const float4*)(x + (size_t)grow * IND + kt + kq * 4);
      }
#pragma unroll
      for (int i = 0; i < 2; ++i) {
        int flat = i * 256 + tid, col = flat >> 2, kc = flat & 3;
        rbh[i] = *(const uint4*)(Wth + (size_t)col * IND + kt + kc * 8);
        rbl[i] = *(const uint4*)(Wtl + (size_t)col * IND + kt + kc * 8);
      }
    }
    // ---- fragments + 32 MFMA from buf[cur]
    {
      const ushort* bAh = smem + cur * 15360;
      const ushort* bBh = bAh + 5120;
      const ushort* bBl = bAh + 10240;
      short8v ah[4], bh[4], bl[4];
#pragma unroll
      for (int m = 0; m < 4; ++m) {
        int r = wr * 64 + m * 16 + lrow;
        ah[m] = *(const short8v*)&bAh[r * 40 + lkg * 8];
      }
#pragma unroll
      for (int n = 0; n < 4; ++n) {
        int c = wc * 64 + n * 16 + lrow;
        bh[n] = *(const short8v*)&bBh[c * 40 + lkg * 8];
        bl[n] = *(const short8v*)&bBl[c * 40 + lkg * 8];
      }
#pragma unroll
      for (int m = 0; m < 4; ++m)
#pragma unroll
        for (int n = 0; n < 4; ++n) {
          acc[m][n] = __builtin_amdgcn_mfma_f32_16x16x32_bf16(ah[m], bh[n], acc[m][n], 0, 0, 0);
          acc[m][n] = __builtin_amdgcn_mfma_f32_16x16x32_bf16(ah[m], bl[n], acc[m][n], 0, 0, 0);
        }
    }
    // ---- stage next tile into buf[cur^1] (vmcnt waits happen here, after
    //      the MFMA window; next barrier's drain is then nearly free)
    if (s < 15) {
      ushort* dAh = smem + (cur ^ 1) * 15360;
      ushort* dBh = dAh + 5120;
      ushort* dBl = dAh + 10240;
#pragma unroll
      for (int i = 0; i < 4; ++i) {
        int flat = i * 256 + tid, r = flat >> 3, kq = flat & 7;
        ushort4 hi;
        hi.x = f2bf_n(ra[i].x); hi.y = f2bf_n(ra[i].y);
        hi.z = f2bf_n(ra[i].z); hi.w = f2bf_n(ra[i].w);
        *(ushort4*)&dAh[r * 40 + kq * 4] = hi;
      }
#pragma unroll
      for (int i = 0; i < 2; ++i) {
        int flat = i * 256 + tid, col = flat >> 2, kc = flat & 3;
        *(uint4*)&dBh[col * 40 + kc * 8] = rbh[i];
        *(uint4*)&dBl[col * 40 + kc * 8] = rbl[i];
      }
    }
    cur ^= 1;
  }

  // ---- epilogue: stage in LDS, flush with instruction-linear stores
  __syncthreads();  // all waves done reading smem before aliasing as sOut
#pragma unroll
  for (int m = 0; m < 4; ++m)
#pragma unroll
    for (int i = 0; i < 4; ++i) {
      int lr = wr * 64 + m * 16 + lkg * 4 + i;
#pragma unroll
      for (int n = 0; n < 4; ++n)
        sOut[lr * 136 + wc * 64 + n * 16 + lrow] = f2bf_n(acc[m][n][i]);
    }
  __syncthreads();
#pragma unroll
  for (int j = 0; j < 8; ++j) {
    int flat = j * 256 + tid;        // 2048 chunks of 16B: 128 rows x 16
    int r = flat >> 4, c = flat & 15;
    int grow = row0 + r;
    if (grow < NN)
      *(uint4*)(h1b + (size_t)grow * HID + c * 8) =
          *(const uint4*)&sOut[r * 136 + c * 8];
  }
}

// ---------------- CSR build pass 1: partition binning -----------------------
__global__ __launch_bounds__(256) void k_bin(const int* __restrict__ edges,
                                             const int* __restrict__ flag,
                                             int* __restrict__ gCursor,
                                             int* __restrict__ staging) {
  __shared__ int cnt[NP], scn[NP], base[NP], cur[NP];
  __shared__ int items[BINCH];  // 32 KB
  const int tid = threadIdx.x;
  const int e0 = blockIdx.x * BINCH;
  const int ecnt = min(BINCH, NE - e0);
  const int f = *flag;
  for (int i = tid; i < NP; i += 256) cnt[i] = 0;
  __syncthreads();
  for (int i = tid; i < ecnt; i += 256) {
    int d = edge_at(edges, f, NE + e0 + i);
    atomicAdd(&cnt[d >> 10], 1);
  }
  __syncthreads();
  if (tid == 0) {
    int s = 0;
    for (int p = 0; p < NP; ++p) { scn[p] = s; s += cnt[p]; }
  }
  __syncthreads();
  if (tid < NP) {
    base[tid] = (cnt[tid] > 0) ? atomicAdd(&gCursor[tid], cnt[tid]) : 0;
    cur[tid] = 0;
  }
  __syncthreads();
  for (int i = tid; i < ecnt; i += 256) {
    int d = edge_at(edges, f, NE + e0 + i);
    int s = edge_at(edges, f, e0 + i);
    int p = d >> 10;
    int lp = atomicAdd(&cur[p], 1);
    items[scn[p] + lp] = (s << 10) | (d & (PSZ - 1));
  }
  __syncthreads();
  for (int p = 0; p < NP; ++p) {
    int c = cnt[p];
    if (c == 0) continue;
    int gb = base[p];
    int* dst = staging + (size_t)p * PCAP;
    for (int i = tid; i < c; i += 256) {
      int gpos = gb + i;
      if (gpos < PCAP) dst[gpos] = items[scn[p] + i];
    }
  }
}

// ---------------- CSR build pass 2a: scan partition totals ------------------
__global__ void k_partscan(const int* __restrict__ gCursor,
                           int* __restrict__ partBase, int* __restrict__ offsets) {
  __shared__ int s[128];
  int tid = threadIdx.x;
  int v = (tid < NP) ? min(gCursor[tid], PCAP) : 0;
  s[tid] = v;
  __syncthreads();
  for (int off = 1; off < 128; off <<= 1) {
    int t = (tid >= off) ? s[tid - off] : 0;
    __syncthreads();
    s[tid] += t;
    __syncthreads();
  }
  if (tid < NP) partBase[tid] = s[tid] - v;
  if (tid == 0) { partBase[NP] = NE; offsets[NN] = NE; }
}

// ---------------- CSR build pass 2b: per-partition counting sort ------------
__global__ __launch_bounds__(256) void k_csrpart(const int* __restrict__ staging,
                                                 const int* __restrict__ gCursor,
                                                 const int* __restrict__ partBase,
                                                 int* __restrict__ offsets,
                                                 int* __restrict__ csr_src) {
  __shared__ int cnt[PSZ];       // becomes exclusive scan
  __shared__ int cur[PSZ];
  __shared__ int tsum[256];
  __shared__ int srcbuf[PCAP];   // 80 KB
  const int tid = threadIdx.x;
  const int p = blockIdx.x;
  const int tot = min(gCursor[p], PCAP);
  const int gbase = partBase[p];
  const int* st = staging + (size_t)p * PCAP;
  for (int i = tid; i < PSZ; i += 256) { cnt[i] = 0; cur[i] = 0; }
  __syncthreads();
  for (int i = tid; i < tot; i += 256) atomicAdd(&cnt[st[i] & (PSZ - 1)], 1);
  __syncthreads();
  int b0 = tid * 4;
  int c0 = cnt[b0], c1 = cnt[b0 + 1], c2 = cnt[b0 + 2], c3 = cnt[b0 + 3];
  int ls = c0 + c1 + c2 + c3;
  tsum[tid] = ls;
  __syncthreads();
  for (int off = 1; off < 256; off <<= 1) {
    int t = (tid >= off) ? tsum[tid - off] : 0;
    __syncthreads();
    tsum[tid] += t;
    __syncthreads();
  }
  int ebase = tsum[tid] - ls;
  cnt[b0] = ebase;
  cnt[b0 + 1] = ebase + c0;
  cnt[b0 + 2] = ebase + c0 + c1;
  cnt[b0 + 3] = ebase + c0 + c1 + c2;
  __syncthreads();
  for (int i = tid; i < PSZ; i += 256) {
    int node = p * PSZ + i;
    if (node < NN) offsets[node] = gbase + cnt[i];
  }
  for (int i = tid; i < tot; i += 256) {
    int item = st[i];
    int dl = item & (PSZ - 1);
    int lp = atomicAdd(&cur[dl], 1);
    srcbuf[cnt[dl] + lp] = item >> 10;
  }
  __syncthreads();
  for (int i = tid; i < tot; i += 256) csr_src[gbase + i] = srcbuf[i];
}

// ---------------- Aggregation 1 (+b1): aggb[n] = bf16(sum h1[src] + b1) ----
__global__ __launch_bounds__(256) void k_agg1(const ushort* __restrict__ h1b,
                                              const int* __restrict__ offsets,
                                              const int* __restrict__ csr_src,
                                              const float* __restrict__ b1,
                                              ushort* __restrict__ aggb) {
  int w = threadIdx.x >> 6, lane = threadIdx.x & 63;
  int n = blockIdx.x * 4 + w;
  if (n >= NN) return;
  int beg = offsets[n], end = offsets[n + 1];
  const uint* h = (const uint*)h1b;
  float2 acc = ((const float2*)b1)[lane];
  int i = beg;
  for (; i + 1 < end; i += 2) {
    uint v0 = h[(size_t)csr_src[i] * 64 + lane];
    uint v1 = h[(size_t)csr_src[i + 1] * 64 + lane];
    acc.x += __uint_as_float(v0 << 16) + __uint_as_float(v1 << 16);
    acc.y += __uint_as_float(v0 & 0xffff0000u) + __uint_as_float(v1 & 0xffff0000u);
  }
  if (i < end) {
    uint v = h[(size_t)csr_src[i] * 64 + lane];
    acc.x += __uint_as_float(v << 16);
    acc.y += __uint_as_float(v & 0xffff0000u);
  }
  uint o = (uint)f2bf_n(acc.x) | ((uint)f2bf_n(acc.y) << 16);
  ((uint*)aggb)[(size_t)n * 64 + lane] = o;
}

// ---------------- BN stats (bf16 input) ------------------------------------
__global__ __launch_bounds__(256) void k_bnstats(const ushort* __restrict__ aggb,
                                                 float* __restrict__ gsum,
                                                 float* __restrict__ gsq) {
  __shared__ float2 ss[4][64], qq[4][64];
  int tid = threadIdx.x;
  int lane = tid & 63, g = tid >> 6;
  int r0 = blockIdx.x * 128;
  const uint* a = (const uint*)aggb;
  float2 s = {0.f, 0.f}, q = {0.f, 0.f};
  for (int k = 0; k < 32; ++k) {
    int r = r0 + g + 4 * k;
    if (r < NN) {
      uint v = a[(size_t)r * 64 + lane];
      float lo = __uint_as_float(v << 16);
      float hi = __uint_as_float(v & 0xffff0000u);
      s.x += lo; s.y += hi;
      q.x += lo * lo; q.y += hi * hi;
    }
  }
  ss[g][lane] = s; qq[g][lane] = q;
  __syncthreads();
  if (g == 0) {
    float2 S = ss[0][lane], Q = qq[0][lane];
#pragma unroll
    for (int gg = 1; gg < 4; ++gg) {
      S.x += ss[gg][lane].x; S.y += ss[gg][lane].y;
      Q.x += qq[gg][lane].x; Q.y += qq[gg][lane].y;
    }
    atomicAdd(&gsum[2 * lane], S.x);
    atomicAdd(&gsum[2 * lane + 1], S.y);
    atomicAdd(&gsq[2 * lane], Q.x);
    atomicAdd(&gsq[2 * lane + 1], Q.y);
  }
}

__global__ void k_bnfin(const float* __restrict__ gsum, const float* __restrict__ gsq,
                        const float* __restrict__ gamma, const float* __restrict__ beta,
                        float* __restrict__ isg, float* __restrict__ bb) {
  int c = threadIdx.x;  // 128 threads
  float mean = gsum[c] * (1.f / NN);
  float var = gsq[c] * (1.f / NN) - mean * mean;
  var = fmaxf(var, 0.f);
  float inv = 1.f / sqrtf(var + BN_EPS);
  float g = gamma[c] * inv;
  isg[c] = g;
  bb[c] = beta[c] - mean * g;
}

// ---------------- GEMM2 (BN+ReLU fused, bf16 A): h2b = bf16(relu(bn(aggb))@W2)
__global__ __launch_bounds__(256) void k_gemm2(const ushort* __restrict__ aggb,
                                               const float* __restrict__ W2,
                                               const float* __restrict__ isg,
                                               const float* __restrict__ bb,
                                               ushort* __restrict__ h2b) {
  __shared__ float As[32][132];
  __shared__ float Bs[32][68];
  __shared__ float isgS[128], bbS[128];
  const int tid = threadIdx.x;
  if (tid < 128) { isgS[tid] = isg[tid]; bbS[tid] = bb[tid]; }
  __syncthreads();
  const int tr = tid >> 4, tc = tid & 15;
  const int row0 = blockIdx.x * 128;
  float acc[8][4];
#pragma unroll
  for (int i = 0; i < 8; ++i)
#pragma unroll
    for (int j = 0; j < 4; ++j) acc[i][j] = 0.f;

  for (int kt = 0; kt < HID; kt += 32) {
#pragma unroll
    for (int rr = 0; rr < 4; ++rr) {
      int idx = tid + rr * 256;
      int r = idx >> 3;
      int c = (idx & 7) << 2;
      int row = row0 + r; if (row > NN - 1) row = NN - 1;
      ushort4 v4 = *(const ushort4*)(aggb + (size_t)row * HID + kt + c);
      int k0 = kt + c;
      float vx = fmaxf(fmaf(bf2f(v4.x), isgS[k0 + 0], bbS[k0 + 0]), 0.f);
      float vy = fmaxf(fmaf(bf2f(v4.y), isgS[k0 + 1], bbS[k0 + 1]), 0.f);
      float vz = fmaxf(fmaf(bf2f(v4.z), isgS[k0 + 2], bbS[k0 + 2]), 0.f);
      float vw = fmaxf(fmaf(bf2f(v4.w), isgS[k0 + 3], bbS[k0 + 3]), 0.f);
      As[c + 0][r] = vx; As[c + 1][r] = vy;
      As[c + 2][r] = vz; As[c + 3][r] = vw;
    }
#pragma unroll
    for (int rr = 0; rr < 2; ++rr) {
      int idx = tid + rr * 256;
      int kk = idx >> 4;
      int cc = (idx & 15) << 2;
      *(float4*)&Bs[kk][cc] = *(const float4*)(W2 + (size_t)(kt + kk) * OUTD + cc);
    }
    __syncthreads();
#pragma unroll
    for (int kk = 0; kk < 32; ++kk) {
      float a[8], b[4];
      *(float4*)&a[0] = *(const float4*)&As[kk][tr * 8];
      *(float4*)&a[4] = *(const float4*)&As[kk][tr * 8 + 4];
      *(float4*)&b[0] = *(const float4*)&Bs[kk][tc * 4];
#pragma unroll
      for (int i = 0; i < 8; ++i)
#pragma unroll
        for (int j = 0; j < 4; ++j) acc[i][j] = fmaf(a[i], b[j], acc[i][j]);
    }
    __syncthreads();
  }
#pragma unroll
  for (int i = 0; i < 8; ++i) {
    int row = row0 + tr * 8 + i;
    if (row < NN) {
      ushort4 o;
      o.x = f2bf_n(acc[i][0]); o.y = f2bf_n(acc[i][1]);
      o.z = f2bf_n(acc[i][2]); o.w = f2bf_n(acc[i][3]);
      *(ushort4*)(h2b + (size_t)row * OUTD + tc * 4) = o;
    }
  }
}

// ---------------- Aggregation 2 + b2 + L2 normalize + fp32 store -----------
__global__ __launch_bounds__(256) void k_agg2norm(const ushort* __restrict__ h2b,
                                                  const int* __restrict__ offsets,
                                                  const int* __restrict__ csr_src,
                                                  const float* __restrict__ b2,
                                                  float* __restrict__ out) {
  int w = threadIdx.x >> 6, lane = threadIdx.x & 63;
  int n = blockIdx.x * 4 + w;
  if (n >= NN) return;
  int beg = offsets[n], end = offsets[n + 1];
  float acc = b2[lane];
  int i = beg;
  for (; i + 1 < end; i += 2) {
    acc += bf2f(h2b[(size_t)csr_src[i] * OUTD + lane]) +
           bf2f(h2b[(size_t)csr_src[i + 1] * OUTD + lane]);
  }
  if (i < end) acc += bf2f(h2b[(size_t)csr_src[i] * OUTD + lane]);
  float q = acc * acc;
#pragma unroll
  for (int off = 32; off > 0; off >>= 1) q += __shfl_xor(q, off);
  float norm = sqrtf(q);
  float scale = 1.f / fmaxf(norm, 1e-12f);
  out[(size_t)n * OUTD + lane] = acc * scale;
}

// ---------------- launch ----------------------------------------------------
extern "C" void kernel_launch(void* const* d_in, const int* in_sizes, int n_in,
                              void* d_out, int out_size, void* d_ws, size_t ws_size,
                              hipStream_t stream) {
  const float* x     = (const float*)d_in[0];
  const int*   edges = (const int*)d_in[1];
  const float* W1    = (const float*)d_in[2];
  const float* b1    = (const float*)d_in[3];
  const float* W2    = (const float*)d_in[4];
  const float* b2    = (const float*)d_in[5];
  const float* gamma = (const float*)d_in[6];
  const float* beta  = (const float*)d_in[7];

  char* ws = (char*)d_ws;
  ushort* h1b     = (ushort*)(ws);                // 25.6 MB
  ushort* aggb    = (ushort*)(ws + 26000000);     // 25.6 MB (bf16)
  int*    csr_src = (int*)(ws + 77500000);        // 6.4 MB
  int*    offsets = (int*)(ws + 84000000);        // 100001 ints
  int*    staging = (int*)(ws + 84400128);        // 98*20480*4 = 8,028,160 B
  int*    gCursor = (int*)(ws + 92428544);        // 98 ints (512B region)
  int*    partBase= (int*)(ws + 92429056);        // 99 ints (512B region)
  float*  gsum    = (float*)(ws + 92429568);      // 128 f
  float*  gsq     = (float*)(ws + 92430080);      // 128 f
  float*  isg     = (float*)(ws + 92430592);      // 128 f
  float*  bbv     = (float*)(ws + 92431104);      // 128 f
  int*    eflag   = (int*)(ws + 92431616);        // 1 int
  ushort* Wth     = (ushort*)(ws + 92432128);     // 128 KB
  ushort* Wtl     = (ushort*)(ws + 92563200);     // 128 KB
  ushort* h2b     = h1b;                          // reuse (h1b dead after agg1)

  if (ws_size < 92700000) return;  // scratch layout requirement

  // zero gCursor + partBase + gsum + gsq (2 KB)
  hipMemsetAsync(gCursor, 0, 2048, stream);

  k_detect<<<1, 64, 0, stream>>>(edges, eflag);
  k_prepW<<<256, 256, 0, stream>>>(W1, Wth, Wtl);
  k_gemm1m<<<782, 256, 0, stream>>>(x, Wth, Wtl, h1b);
  k_bin<<<196, 256, 0, stream>>>(edges, eflag, gCursor, staging);
  k_partscan<<<1, 128, 0, stream>>>(gCursor, partBase, offsets);
  k_csrpart<<<NP, 256, 0, stream>>>(staging, gCursor, partBase, offsets, csr_src);
  k_agg1<<<25000, 256, 0, stream>>>(h1b, offsets, csr_src, b1, aggb);
  k_bnstats<<<782, 256, 0, stream>>>(aggb, gsum, gsq);
  k_bnfin<<<1, 128, 0, stream>>>(gsum, gsq, gamma, beta, isg, bbv);
  k_gemm2<<<782, 256, 0, stream>>>(aggb, W2, isg, bbv, h2b);
  k_agg2norm<<<25000, 256, 0, stream>>>(h2b, offsets, csr_src, b2,
                                        (float*)d_out);
}

// Round 11
// 315.321 us; speedup vs baseline: 1.6476x; 1.3346x over previous
//
#include <hip/hip_runtime.h>
#include <hip/hip_bf16.h>
#include <stdint.h>

#define NN 100000
#define NE 1600000
#define IND 512
#define HID 128
#define OUTD 64
#define BN_EPS 1e-5f
#define NP 98        // ceil(NN/1024) dst partitions
#define PSZ 1024     // nodes per partition
#define PCAP 20480   // staging capacity per partition
#define BINCH 8192   // edges per bin block
#define NBIN 196     // ceil(NE/BINCH)

typedef __attribute__((ext_vector_type(8))) short short8v;
typedef __attribute__((ext_vector_type(4))) float f32x4;

// ---- fp32 -> bf16 (RNE) ----------------------------------------------------
__device__ __forceinline__ ushort f2bf(float f, float& back) {
  uint u = __float_as_uint(f);
  uint r = u + 0x7FFFu + ((u >> 16) & 1u);
  ushort h = (ushort)(r >> 16);
  back = __uint_as_float(((uint)h) << 16);
  return h;
}
__device__ __forceinline__ ushort f2bf_n(float f) {
  uint u = __float_as_uint(f);
  uint r = u + 0x7FFFu + ((u >> 16) & 1u);
  return (ushort)(r >> 16);
}
__device__ __forceinline__ float bf2f(ushort h) {
  return __uint_as_float(((uint)h) << 16);
}
__device__ __forceinline__ uint packbf(float lo, float hi) {
  return (uint)f2bf_n(lo) | ((uint)f2bf_n(hi) << 16);
}

__device__ __forceinline__ int edge_at(const int* e32, int f, int i) {
  if (f) return (int)((const long long*)e32)[i];
  return e32[i];
}

// ---------------- K0: detect + prepW(W1^T hi/lo) + prepW2(W2^T hi/lo) -------
__global__ __launch_bounds__(256) void k_prep(const int* __restrict__ edges,
                                              const float* __restrict__ W1,
                                              const float* __restrict__ W2,
                                              int* __restrict__ flag,
                                              ushort* __restrict__ Wth,
                                              ushort* __restrict__ Wtl,
                                              ushort* __restrict__ W2th,
                                              ushort* __restrict__ W2tl) {
  const int bid = blockIdx.x, tid = threadIdx.x;
  if (bid == 0) {
    __shared__ int nz;
    if (tid == 0) nz = 0;
    __syncthreads();
    if (tid < 64) {
      int v = edges[2 * tid + 1];
      if (v != 0) atomicAdd(&nz, 1);
    }
    __syncthreads();
    if (tid == 0) *flag = (nz == 0) ? 1 : 0;  // 1 => int64
    return;
  }
  if (bid <= 256) {  // W1^T: [n][k], 128*512
    int i = (bid - 1) * 256 + tid;
    int n = i >> 9, k = i & 511;
    float w = W1[(size_t)k * HID + n];
    float back;
    Wth[i] = f2bf(w, back);
    Wtl[i] = f2bf_n(w - back);
    return;
  }
  {  // W2^T: [n][k], 64*128
    int j = (bid - 257) * 256 + tid;
    int n = j >> 7, k = j & 127;
    float w = W2[(size_t)k * OUTD + n];
    float back;
    W2th[j] = f2bf(w, back);
    W2tl[j] = f2bf_n(w - back);
  }
}

// ---------------- K1 body A: CSR bin pass (blocks 0..195) -------------------
__device__ void bin_body(int bid, ushort* smem16, const int* edges,
                         const int* flag, int* gCursor, int* staging) {
  int* cnt   = (int*)smem16;        // [NP]
  int* scn   = cnt + 128;           // [NP]
  int* base  = cnt + 256;           // [NP]
  int* cur   = cnt + 384;           // [NP]
  int* items = cnt + 512;           // [BINCH] -> total (512+8192)*4 = 34816 B
  const int tid = threadIdx.x;
  const int e0 = bid * BINCH;
  const int ecnt = min(BINCH, NE - e0);
  const int f = *flag;
  for (int i = tid; i < NP; i += 256) cnt[i] = 0;
  __syncthreads();
  for (int i = tid; i < ecnt; i += 256) {
    int d = edge_at(edges, f, NE + e0 + i);
    atomicAdd(&cnt[d >> 10], 1);
  }
  __syncthreads();
  if (tid == 0) {
    int s = 0;
    for (int p = 0; p < NP; ++p) { scn[p] = s; s += cnt[p]; }
  }
  __syncthreads();
  if (tid < NP) {
    base[tid] = (cnt[tid] > 0) ? atomicAdd(&gCursor[tid], cnt[tid]) : 0;
    cur[tid] = 0;
  }
  __syncthreads();
  for (int i = tid; i < ecnt; i += 256) {
    int d = edge_at(edges, f, NE + e0 + i);
    int s = edge_at(edges, f, e0 + i);
    int p = d >> 10;
    int lp = atomicAdd(&cur[p], 1);
    items[scn[p] + lp] = (s << 10) | (d & (PSZ - 1));
  }
  __syncthreads();
  for (int p = 0; p < NP; ++p) {
    int c = cnt[p];
    if (c == 0) continue;
    int gb = base[p];
    int* dst = staging + (size_t)p * PCAP;
    for (int i = tid; i < c; i += 256) {
      int gpos = gb + i;
      if (gpos < PCAP) dst[gpos] = items[scn[p] + i];
    }
  }
}

// ---------------- K1 body B: GEMM1 (r10 double-buffered, proven) ------------
__device__ void gemm1_body(int bid, ushort* smem, const float* x,
                           const ushort* Wth, const ushort* Wtl,
                           ushort* h1b) {
  ushort* sOut = smem;
  const int tid = threadIdx.x;
  const int lane = tid & 63, wid = tid >> 6;
  const int wr = wid >> 1, wc = wid & 1;
  const int lrow = lane & 15, lkg = lane >> 4;
  const int row0 = bid * 128;

  f32x4 acc[4][4];
#pragma unroll
  for (int m = 0; m < 4; ++m)
#pragma unroll
    for (int n = 0; n < 4; ++n) acc[m][n] = (f32x4){0.f, 0.f, 0.f, 0.f};

  float4 ra[4];
  uint4 rbh[2], rbl[2];

#pragma unroll
  for (int i = 0; i < 4; ++i) {
    int flat = i * 256 + tid, r = flat >> 3, kq = flat & 7;
    int grow = row0 + r; if (grow > NN - 1) grow = NN - 1;
    ra[i] = *(const float4*)(x + (size_t)grow * IND + kq * 4);
  }
#pragma unroll
  for (int i = 0; i < 2; ++i) {
    int flat = i * 256 + tid, col = flat >> 2, kc = flat & 3;
    rbh[i] = *(const uint4*)(Wth + (size_t)col * IND + kc * 8);
    rbl[i] = *(const uint4*)(Wtl + (size_t)col * IND + kc * 8);
  }
  {
    ushort* dAh = smem;
    ushort* dBh = smem + 5120;
    ushort* dBl = smem + 10240;
#pragma unroll
    for (int i = 0; i < 4; ++i) {
      int flat = i * 256 + tid, r = flat >> 3, kq = flat & 7;
      ushort4 hi;
      hi.x = f2bf_n(ra[i].x); hi.y = f2bf_n(ra[i].y);
      hi.z = f2bf_n(ra[i].z); hi.w = f2bf_n(ra[i].w);
      *(ushort4*)&dAh[r * 40 + kq * 4] = hi;
    }
#pragma unroll
    for (int i = 0; i < 2; ++i) {
      int flat = i * 256 + tid, col = flat >> 2, kc = flat & 3;
      *(uint4*)&dBh[col * 40 + kc * 8] = rbh[i];
      *(uint4*)&dBl[col * 40 + kc * 8] = rbl[i];
    }
  }

  int cur = 0;
  for (int s = 0; s < 16; ++s) {
    __syncthreads();
    if (s < 15) {
      int kt = (s + 1) * 32;
#pragma unroll
      for (int i = 0; i < 4; ++i) {
        int flat = i * 256 + tid, r = flat >> 3, kq = flat & 7;
        int grow = row0 + r; if (grow > NN - 1) grow = NN - 1;
        ra[i] = *(const float4*)(x + (size_t)grow * IND + kt + kq * 4);
      }
#pragma unroll
      for (int i = 0; i < 2; ++i) {
        int flat = i * 256 + tid, col = flat >> 2, kc = flat & 3;
        rbh[i] = *(const uint4*)(Wth + (size_t)col * IND + kt + kc * 8);
        rbl[i] = *(const uint4*)(Wtl + (size_t)col * IND + kt + kc * 8);
      }
    }
    {
      const ushort* bAh = smem + cur * 15360;
      const ushort* bBh = bAh + 5120;
      const ushort* bBl = bAh + 10240;
      short8v ah[4], bh[4], bl[4];
#pragma unroll
      for (int m = 0; m < 4; ++m) {
        int r = wr * 64 + m * 16 + lrow;
        ah[m] = *(const short8v*)&bAh[r * 40 + lkg * 8];
      }
#pragma unroll
      for (int n = 0; n < 4; ++n) {
        int c = wc * 64 + n * 16 + lrow;
        bh[n] = *(const short8v*)&bBh[c * 40 + lkg * 8];
        bl[n] = *(const short8v*)&bBl[c * 40 + lkg * 8];
      }
#pragma unroll
      for (int m = 0; m < 4; ++m)
#pragma unroll
        for (int n = 0; n < 4; ++n) {
          acc[m][n] = __builtin_amdgcn_mfma_f32_16x16x32_bf16(ah[m], bh[n], acc[m][n], 0, 0, 0);
          acc[m][n] = __builtin_amdgcn_mfma_f32_16x16x32_bf16(ah[m], bl[n], acc[m][n], 0, 0, 0);
        }
    }
    if (s < 15) {
      ushort* dAh = smem + (cur ^ 1) * 15360;
      ushort* dBh = dAh + 5120;
      ushort* dBl = dAh + 10240;
#pragma unroll
      for (int i = 0; i < 4; ++i) {
        int flat = i * 256 + tid, r = flat >> 3, kq = flat & 7;
        ushort4 hi;
        hi.x = f2bf_n(ra[i].x); hi.y = f2bf_n(ra[i].y);
        hi.z = f2bf_n(ra[i].z); hi.w = f2bf_n(ra[i].w);
        *(ushort4*)&dAh[r * 40 + kq * 4] = hi;
      }
#pragma unroll
      for (int i = 0; i < 2; ++i) {
        int flat = i * 256 + tid, col = flat >> 2, kc = flat & 3;
        *(uint4*)&dBh[col * 40 + kc * 8] = rbh[i];
        *(uint4*)&dBl[col * 40 + kc * 8] = rbl[i];
      }
    }
    cur ^= 1;
  }

  __syncthreads();
#pragma unroll
  for (int m = 0; m < 4; ++m)
#pragma unroll
    for (int i = 0; i < 4; ++i) {
      int lr = wr * 64 + m * 16 + lkg * 4 + i;
#pragma unroll
      for (int n = 0; n < 4; ++n)
        sOut[lr * 136 + wc * 64 + n * 16 + lrow] = f2bf_n(acc[m][n][i]);
    }
  __syncthreads();
#pragma unroll
  for (int j = 0; j < 8; ++j) {
    int flat = j * 256 + tid;
    int r = flat >> 4, c = flat & 15;
    int grow = row0 + r;
    if (grow < NN)
      *(uint4*)(h1b + (size_t)grow * HID + c * 8) =
          *(const uint4*)&sOut[r * 136 + c * 8];
  }
}

// ---------------- K1: fused bin (first) + gemm1 -----------------------------
__global__ __launch_bounds__(256) void k_fused1(const float* __restrict__ x,
                                                const ushort* __restrict__ Wth,
                                                const ushort* __restrict__ Wtl,
                                                const int* __restrict__ edges,
                                                const int* __restrict__ flag,
                                                int* __restrict__ gCursor,
                                                int* __restrict__ staging,
                                                ushort* __restrict__ h1b) {
  __shared__ __align__(16) ushort smem[30720];  // gemm: 2x15360; bin: 34816B
  if (blockIdx.x < NBIN)
    bin_body(blockIdx.x, smem, edges, flag, gCursor, staging);
  else
    gemm1_body(blockIdx.x - NBIN, smem, x, Wth, Wtl, h1b);
}

// ---------------- CSR pass 2a: scan partition totals ------------------------
__global__ void k_partscan(const int* __restrict__ gCursor,
                           int* __restrict__ partBase, int* __restrict__ offsets) {
  __shared__ int s[128];
  int tid = threadIdx.x;
  int v = (tid < NP) ? min(gCursor[tid], PCAP) : 0;
  s[tid] = v;
  __syncthreads();
  for (int off = 1; off < 128; off <<= 1) {
    int t = (tid >= off) ? s[tid - off] : 0;
    __syncthreads();
    s[tid] += t;
    __syncthreads();
  }
  if (tid < NP) partBase[tid] = s[tid] - v;
  if (tid == 0) { partBase[NP] = NE; offsets[NN] = NE; }
}

// ---------------- CSR pass 2b: per-partition counting sort ------------------
__global__ __launch_bounds__(256) void k_csrpart(const int* __restrict__ staging,
                                                 const int* __restrict__ gCursor,
                                                 const int* __restrict__ partBase,
                                                 int* __restrict__ offsets,
                                                 int* __restrict__ csr_src) {
  __shared__ int cnt[PSZ];
  __shared__ int cur[PSZ];
  __shared__ int tsum[256];
  __shared__ int srcbuf[PCAP];   // 80 KB
  const int tid = threadIdx.x;
  const int p = blockIdx.x;
  const int tot = min(gCursor[p], PCAP);
  const int gbase = partBase[p];
  const int* st = staging + (size_t)p * PCAP;
  for (int i = tid; i < PSZ; i += 256) { cnt[i] = 0; cur[i] = 0; }
  __syncthreads();
  for (int i = tid; i < tot; i += 256) atomicAdd(&cnt[st[i] & (PSZ - 1)], 1);
  __syncthreads();
  int b0 = tid * 4;
  int c0 = cnt[b0], c1 = cnt[b0 + 1], c2 = cnt[b0 + 2], c3 = cnt[b0 + 3];
  int ls = c0 + c1 + c2 + c3;
  tsum[tid] = ls;
  __syncthreads();
  for (int off = 1; off < 256; off <<= 1) {
    int t = (tid >= off) ? tsum[tid - off] : 0;
    __syncthreads();
    tsum[tid] += t;
    __syncthreads();
  }
  int ebase = tsum[tid] - ls;
  cnt[b0] = ebase;
  cnt[b0 + 1] = ebase + c0;
  cnt[b0 + 2] = ebase + c0 + c1;
  cnt[b0 + 3] = ebase + c0 + c1 + c2;
  __syncthreads();
  for (int i = tid; i < PSZ; i += 256) {
    int node = p * PSZ + i;
    if (node < NN) offsets[node] = gbase + cnt[i];
  }
  for (int i = tid; i < tot; i += 256) {
    int item = st[i];
    int dl = item & (PSZ - 1);
    int lp = atomicAdd(&cur[dl], 1);
    srcbuf[cnt[dl] + lp] = item >> 10;
  }
  __syncthreads();
  for (int i = tid; i < tot; i += 256) csr_src[gbase + i] = srcbuf[i];
}

// ---------------- Aggregation 1 (+b1): aggb[n] = bf16(sum h1[src] + b1) ----
__global__ __launch_bounds__(256) void k_agg1(const ushort* __restrict__ h1b,
                                              const int* __restrict__ offsets,
                                              const int* __restrict__ csr_src,
                                              const float* __restrict__ b1,
                                              ushort* __restrict__ aggb) {
  int w = threadIdx.x >> 6, lane = threadIdx.x & 63;
  int n = blockIdx.x * 4 + w;
  if (n >= NN) return;
  int beg = offsets[n], end = offsets[n + 1];
  const uint* h = (const uint*)h1b;
  float2 a0 = ((const float2*)b1)[lane];
  float2 a1 = {0.f, 0.f};
  int i = beg;
  for (; i + 3 < end; i += 4) {
    uint v0 = h[(size_t)csr_src[i] * 64 + lane];
    uint v1 = h[(size_t)csr_src[i + 1] * 64 + lane];
    uint v2 = h[(size_t)csr_src[i + 2] * 64 + lane];
    uint v3 = h[(size_t)csr_src[i + 3] * 64 + lane];
    a0.x += __uint_as_float(v0 << 16) + __uint_as_float(v1 << 16);
    a0.y += __uint_as_float(v0 & 0xffff0000u) + __uint_as_float(v1 & 0xffff0000u);
    a1.x += __uint_as_float(v2 << 16) + __uint_as_float(v3 << 16);
    a1.y += __uint_as_float(v2 & 0xffff0000u) + __uint_as_float(v3 & 0xffff0000u);
  }
  for (; i < end; ++i) {
    uint v = h[(size_t)csr_src[i] * 64 + lane];
    a0.x += __uint_as_float(v << 16);
    a0.y += __uint_as_float(v & 0xffff0000u);
  }
  a0.x += a1.x; a0.y += a1.y;
  ((uint*)aggb)[(size_t)n * 64 + lane] = packbf(a0.x, a0.y);
}

// ---------------- BN stats (bf16 input) ------------------------------------
__global__ __launch_bounds__(256) void k_bnstats(const ushort* __restrict__ aggb,
                                                 float* __restrict__ gsum,
                                                 float* __restrict__ gsq) {
  __shared__ float2 ss[4][64], qq[4][64];
  int tid = threadIdx.x;
  int lane = tid & 63, g = tid >> 6;
  int r0 = blockIdx.x * 128;
  const uint* a = (const uint*)aggb;
  float2 s = {0.f, 0.f}, q = {0.f, 0.f};
  for (int k = 0; k < 32; ++k) {
    int r = r0 + g + 4 * k;
    if (r < NN) {
      uint v = a[(size_t)r * 64 + lane];
      float lo = __uint_as_float(v << 16);
      float hi = __uint_as_float(v & 0xffff0000u);
      s.x += lo; s.y += hi;
      q.x += lo * lo; q.y += hi * hi;
    }
  }
  ss[g][lane] = s; qq[g][lane] = q;
  __syncthreads();
  if (g == 0) {
    float2 S = ss[0][lane], Q = qq[0][lane];
#pragma unroll
    for (int gg = 1; gg < 4; ++gg) {
      S.x += ss[gg][lane].x; S.y += ss[gg][lane].y;
      Q.x += qq[gg][lane].x; Q.y += qq[gg][lane].y;
    }
    atomicAdd(&gsum[2 * lane], S.x);
    atomicAdd(&gsum[2 * lane + 1], S.y);
    atomicAdd(&gsq[2 * lane], Q.x);
    atomicAdd(&gsq[2 * lane + 1], Q.y);
  }
}

__global__ void k_bnfin(const float* __restrict__ gsum, const float* __restrict__ gsq,
                        const float* __restrict__ gamma, const float* __restrict__ beta,
                        float* __restrict__ isg, float* __restrict__ bb) {
  int c = threadIdx.x;  // 128 threads
  float mean = gsum[c] * (1.f / NN);
  float var = gsq[c] * (1.f / NN) - mean * mean;
  var = fmaxf(var, 0.f);
  float inv = 1.f / sqrtf(var + BN_EPS);
  float g = gamma[c] * inv;
  isg[c] = g;
  bb[c] = beta[c] - mean * g;
}

// ---------------- GEMM2 via MFMA: h2b = bf16(relu(bn(aggb)) @ W2) -----------
// BM=128, BN=64, BK=32, 4 K-steps. 4 waves (2x2), wave tile 64x32.
// B (W2^T hi/lo) resident in LDS for the whole kernel; A double-buffered.
__global__ __launch_bounds__(256) void k_gemm2m(const ushort* __restrict__ aggb,
                                                const ushort* __restrict__ W2th,
                                                const ushort* __restrict__ W2tl,
                                                const float* __restrict__ isg,
                                                const float* __restrict__ bb,
                                                ushort* __restrict__ h2b) {
  __shared__ __align__(16) ushort smem[27648]; // Bh 8704 | Bl 8704 | Adbuf 10240
  __shared__ float isgS[128], bbS[128];
  ushort* sBh = smem;            // [64][136]
  ushort* sBl = smem + 8704;     // [64][136]
  ushort* sA  = smem + 17408;    // 2 x [128][40]
  ushort* sOut = sA;             // epilogue alias: [128][72] = 9216 u16
  const int tid = threadIdx.x;
  const int lane = tid & 63, wid = tid >> 6;
  const int wr = wid >> 1, wc = wid & 1;
  const int lrow = lane & 15, lkg = lane >> 4;
  const int row0 = blockIdx.x * 128;

  if (tid < 128) { isgS[tid] = isg[tid]; bbS[tid] = bb[tid]; }
  // stage B: 64 rows x 128 u16 each (hi/lo), 1024 16B-chunks each
#pragma unroll
  for (int i = 0; i < 4; ++i) {
    int c = i * 256 + tid;
    int n = c >> 4, kq = c & 15;
    *(uint4*)&sBh[n * 136 + kq * 8] = *(const uint4*)(W2th + (size_t)n * HID + kq * 8);
    *(uint4*)&sBl[n * 136 + kq * 8] = *(const uint4*)(W2tl + (size_t)n * HID + kq * 8);
  }

  f32x4 acc[4][2];
#pragma unroll
  for (int m = 0; m < 4; ++m)
#pragma unroll
    for (int n = 0; n < 2; ++n) acc[m][n] = (f32x4){0.f, 0.f, 0.f, 0.f};

  // A tile: 128 rows x 32 cols bf16 = 512 16B-chunks; 2 per thread
  uint4 rA[2];
#pragma unroll
  for (int i = 0; i < 2; ++i) {
    int c = i * 256 + tid;
    int r = c >> 2, cq = c & 3;
    int grow = row0 + r; if (grow > NN - 1) grow = NN - 1;
    rA[i] = *(const uint4*)(aggb + (size_t)grow * HID + cq * 8);
  }
  __syncthreads();  // isgS/bbS + B visible

  // BN+ReLU + stage A0 into buf0
  {
    ushort* dA = sA;
#pragma unroll
    for (int i = 0; i < 2; ++i) {
      int c = i * 256 + tid;
      int r = c >> 2, cq = c & 3;
      int k0 = cq * 8;
      uint4 v = rA[i];
      uint o[4];
      const uint* vv = (const uint*)&v;
#pragma unroll
      for (int j = 0; j < 4; ++j) {
        float lo = __uint_as_float(vv[j] << 16);
        float hi = __uint_as_float(vv[j] & 0xffff0000u);
        lo = fmaxf(fmaf(lo, isgS[k0 + 2 * j], bbS[k0 + 2 * j]), 0.f);
        hi = fmaxf(fmaf(hi, isgS[k0 + 2 * j + 1], bbS[k0 + 2 * j + 1]), 0.f);
        o[j] = packbf(lo, hi);
      }
      *(uint4*)&dA[r * 40 + cq * 8] = *(const uint4*)o;
    }
  }

  int cur = 0;
  for (int s = 0; s < 4; ++s) {
    __syncthreads();
    const int kt = s * 32;
    if (s < 3) {
      int ktn = kt + 32;
#pragma unroll
      for (int i = 0; i < 2; ++i) {
        int c = i * 256 + tid;
        int r = c >> 2, cq = c & 3;
        int grow = row0 + r; if (grow > NN - 1) grow = NN - 1;
        rA[i] = *(const uint4*)(aggb + (size_t)grow * HID + ktn + cq * 8);
      }
    }
    {
      const ushort* bA = sA + cur * 5120;
      short8v ah[4], bh[2], bl[2];
#pragma unroll
      for (int m = 0; m < 4; ++m) {
        int r = wr * 64 + m * 16 + lrow;
        ah[m] = *(const short8v*)&bA[r * 40 + lkg * 8];
      }
#pragma unroll
      for (int n = 0; n < 2; ++n) {
        int c = wc * 32 + n * 16 + lrow;
        bh[n] = *(const short8v*)&sBh[c * 136 + kt + lkg * 8];
        bl[n] = *(const short8v*)&sBl[c * 136 + kt + lkg * 8];
      }
#pragma unroll
      for (int m = 0; m < 4; ++m)
#pragma unroll
        for (int n = 0; n < 2; ++n) {
          acc[m][n] = __builtin_amdgcn_mfma_f32_16x16x32_bf16(ah[m], bh[n], acc[m][n], 0, 0, 0);
          acc[m][n] = __builtin_amdgcn_mfma_f32_16x16x32_bf16(ah[m], bl[n], acc[m][n], 0, 0, 0);
        }
    }
    if (s < 3) {
      ushort* dA = sA + (cur ^ 1) * 5120;
      int k0b = (s + 1) * 32;
#pragma unroll
      for (int i = 0; i < 2; ++i) {
        int c = i * 256 + tid;
        int r = c >> 2, cq = c & 3;
        int k0 = k0b + cq * 8;
        uint4 v = rA[i];
        uint o[4];
        const uint* vv = (const uint*)&v;
#pragma unroll
        for (int j = 0; j < 4; ++j) {
          float lo = __uint_as_float(vv[j] << 16);
          float hi = __uint_as_float(vv[j] & 0xffff0000u);
          lo = fmaxf(fmaf(lo, isgS[k0 + 2 * j], bbS[k0 + 2 * j]), 0.f);
          hi = fmaxf(fmaf(hi, isgS[k0 + 2 * j + 1], bbS[k0 + 2 * j + 1]), 0.f);
          o[j] = packbf(lo, hi);
        }
        *(uint4*)&dA[r * 40 + cq * 8] = *(const uint4*)o;
      }
    }
    cur ^= 1;
  }

  // epilogue: stage into LDS (alias A-dbuf), flush coalesced
  __syncthreads();
#pragma unroll
  for (int m = 0; m < 4; ++m)
#pragma unroll
    for (int i = 0; i < 4; ++i) {
      int lr = wr * 64 + m * 16 + lkg * 4 + i;
#pragma unroll
      for (int n = 0; n < 2; ++n)
        sOut[lr * 72 + wc * 32 + n * 16 + lrow] = f2bf_n(acc[m][n][i]);
    }
  __syncthreads();
#pragma unroll
  for (int i = 0; i < 4; ++i) {
    int c = i * 256 + tid;       // 1024 chunks: 128 rows x 8
    int r = c >> 3, cq = c & 7;
    int grow = row0 + r;
    if (grow < NN)
      *(uint4*)(h2b + (size_t)grow * OUTD + cq * 8) =
          *(const uint4*)&sOut[r * 72 + cq * 8];
  }
}

// ---------------- Aggregation 2 + b2 + L2 normalize + fp32 store -----------
__global__ __launch_bounds__(256) void k_agg2norm(const ushort* __restrict__ h2b,
                                                  const int* __restrict__ offsets,
                                                  const int* __restrict__ csr_src,
                                                  const float* __restrict__ b2,
                                                  float* __restrict__ out) {
  int w = threadIdx.x >> 6, lane = threadIdx.x & 63;
  int n = blockIdx.x * 4 + w;
  if (n >= NN) return;
  int beg = offsets[n], end = offsets[n + 1];
  float a0 = b2[lane], a1 = 0.f;
  int i = beg;
  for (; i + 3 < end; i += 4) {
    a0 += bf2f(h2b[(size_t)csr_src[i] * OUTD + lane]) +
          bf2f(h2b[(size_t)csr_src[i + 1] * OUTD + lane]);
    a1 += bf2f(h2b[(size_t)csr_src[i + 2] * OUTD + lane]) +
          bf2f(h2b[(size_t)csr_src[i + 3] * OUTD + lane]);
  }
  for (; i < end; ++i) a0 += bf2f(h2b[(size_t)csr_src[i] * OUTD + lane]);
  float acc = a0 + a1;
  float q = acc * acc;
#pragma unroll
  for (int off = 32; off > 0; off >>= 1) q += __shfl_xor(q, off);
  float norm = sqrtf(q);
  float scale = 1.f / fmaxf(norm, 1e-12f);
  out[(size_t)n * OUTD + lane] = acc * scale;
}

// ---------------- launch ----------------------------------------------------
extern "C" void kernel_launch(void* const* d_in, const int* in_sizes, int n_in,
                              void* d_out, int out_size, void* d_ws, size_t ws_size,
                              hipStream_t stream) {
  const float* x     = (const float*)d_in[0];
  const int*   edges = (const int*)d_in[1];
  const float* W1    = (const float*)d_in[2];
  const float* b1    = (const float*)d_in[3];
  const float* W2    = (const float*)d_in[4];
  const float* b2    = (const float*)d_in[5];
  const float* gamma = (const float*)d_in[6];
  const float* beta  = (const float*)d_in[7];

  char* ws = (char*)d_ws;
  ushort* h1b     = (ushort*)(ws);                // 25.6 MB
  ushort* aggb    = (ushort*)(ws + 26000000);     // 25.6 MB (bf16)
  int*    csr_src = (int*)(ws + 77500000);        // 6.4 MB
  int*    offsets = (int*)(ws + 84000000);        // 100001 ints
  int*    staging = (int*)(ws + 84400128);        // 98*20480*4 = 8,028,160 B
  int*    gCursor = (int*)(ws + 92428544);        // 98 ints (512B region)
  int*    partBase= (int*)(ws + 92429056);        // 99 ints (512B region)
  float*  gsum    = (float*)(ws + 92429568);      // 128 f
  float*  gsq     = (float*)(ws + 92430080);      // 128 f
  float*  isg     = (float*)(ws + 92430592);      // 128 f
  float*  bbv     = (float*)(ws + 92431104);      // 128 f
  int*    eflag   = (int*)(ws + 92431616);        // 1 int
  ushort* Wth     = (ushort*)(ws + 92432128);     // 128 KB
  ushort* Wtl     = (ushort*)(ws + 92563200);     // 128 KB
  ushort* W2th    = (ushort*)(ws + 92694272);     // 16 KB
  ushort* W2tl    = (ushort*)(ws + 92710656);     // 16 KB
  ushort* h2b     = h1b;                          // reuse (h1b dead after agg1)

  if (ws_size < 92727040) return;  // scratch layout requirement

  // zero gCursor + partBase + gsum + gsq (2 KB)
  hipMemsetAsync(gCursor, 0, 2048, stream);

  k_prep<<<289, 256, 0, stream>>>(edges, W1, W2, eflag, Wth, Wtl, W2th, W2tl);
  k_fused1<<<NBIN + 782, 256, 0, stream>>>(x, Wth, Wtl, edges, eflag,
                                           gCursor, staging, h1b);
  k_partscan<<<1, 128, 0, stream>>>(gCursor, partBase, offsets);
  k_csrpart<<<NP, 256, 0, stream>>>(staging, gCursor, partBase, offsets, csr_src);
  k_agg1<<<25000, 256, 0, stream>>>(h1b, offsets, csr_src, b1, aggb);
  k_bnstats<<<782, 256, 0, stream>>>(aggb, gsum, gsq);
  k_bnfin<<<1, 128, 0, stream>>>(gsum, gsq, gamma, beta, isg, bbv);
  k_gemm2m<<<782, 256, 0, stream>>>(aggb, W2th, W2tl, isg, bbv, h2b);
  k_agg2norm<<<25000, 256, 0, stream>>>(h2b, offsets, csr_src, b2,
                                        (float*)d_out);
}

// Round 12
// 309.533 us; speedup vs baseline: 1.6784x; 1.0187x over previous
//
#include <hip/hip_runtime.h>
#include <hip/hip_bf16.h>
#include <stdint.h>

#define NN 100000
#define NE 1600000
#define IND 512
#define HID 128
#define OUTD 64
#define BN_EPS 1e-5f
#define NP 98        // ceil(NN/1024) dst partitions
#define PSZ 1024     // nodes per partition
#define PCAP 20480   // staging capacity per partition
#define BINCH 8192   // edges per bin block
#define NBIN 196     // ceil(NE/BINCH)

typedef __attribute__((ext_vector_type(8))) short short8v;
typedef __attribute__((ext_vector_type(4))) float f32x4;

// ---- fp32 -> bf16 (RNE) ----------------------------------------------------
__device__ __forceinline__ ushort f2bf(float f, float& back) {
  uint u = __float_as_uint(f);
  uint r = u + 0x7FFFu + ((u >> 16) & 1u);
  ushort h = (ushort)(r >> 16);
  back = __uint_as_float(((uint)h) << 16);
  return h;
}
__device__ __forceinline__ ushort f2bf_n(float f) {
  uint u = __float_as_uint(f);
  uint r = u + 0x7FFFu + ((u >> 16) & 1u);
  return (ushort)(r >> 16);
}
__device__ __forceinline__ float bf2f(ushort h) {
  return __uint_as_float(((uint)h) << 16);
}
__device__ __forceinline__ float bflo(uint v) { return __uint_as_float(v << 16); }
__device__ __forceinline__ float bfhi(uint v) { return __uint_as_float(v & 0xffff0000u); }
__device__ __forceinline__ uint packbf(float lo, float hi) {
  return (uint)f2bf_n(lo) | ((uint)f2bf_n(hi) << 16);
}

__device__ __forceinline__ int edge_at(const int* e32, int f, int i) {
  if (f) return (int)((const long long*)e32)[i];
  return e32[i];
}

// ---------------- K0: detect + prepW(W1^T hi/lo) + prepW2(W2^T hi/lo) -------
__global__ __launch_bounds__(256) void k_prep(const int* __restrict__ edges,
                                              const float* __restrict__ W1,
                                              const float* __restrict__ W2,
                                              int* __restrict__ flag,
                                              ushort* __restrict__ Wth,
                                              ushort* __restrict__ Wtl,
                                              ushort* __restrict__ W2th,
                                              ushort* __restrict__ W2tl) {
  const int bid = blockIdx.x, tid = threadIdx.x;
  if (bid == 0) {
    __shared__ int nz;
    if (tid == 0) nz = 0;
    __syncthreads();
    if (tid < 64) {
      int v = edges[2 * tid + 1];
      if (v != 0) atomicAdd(&nz, 1);
    }
    __syncthreads();
    if (tid == 0) *flag = (nz == 0) ? 1 : 0;  // 1 => int64
    return;
  }
  if (bid <= 256) {  // W1^T: [n][k], 128*512
    int i = (bid - 1) * 256 + tid;
    int n = i >> 9, k = i & 511;
    float w = W1[(size_t)k * HID + n];
    float back;
    Wth[i] = f2bf(w, back);
    Wtl[i] = f2bf_n(w - back);
    return;
  }
  {  // W2^T: [n][k], 64*128
    int j = (bid - 257) * 256 + tid;
    int n = j >> 7, k = j & 127;
    float w = W2[(size_t)k * OUTD + n];
    float back;
    W2th[j] = f2bf(w, back);
    W2tl[j] = f2bf_n(w - back);
  }
}

// ---------------- K1 body A: CSR bin pass (blocks 0..195) -------------------
__device__ void bin_body(int bid, ushort* smem16, const int* edges,
                         const int* flag, int* gCursor, int* staging) {
  int* cnt   = (int*)smem16;        // [NP]
  int* scn   = cnt + 128;           // [NP]
  int* base  = cnt + 256;           // [NP]
  int* cur   = cnt + 384;           // [NP]
  int* items = cnt + 512;           // [BINCH]
  const int tid = threadIdx.x;
  const int e0 = bid * BINCH;
  const int ecnt = min(BINCH, NE - e0);
  const int f = *flag;
  for (int i = tid; i < NP; i += 256) cnt[i] = 0;
  __syncthreads();
  for (int i = tid; i < ecnt; i += 256) {
    int d = edge_at(edges, f, NE + e0 + i);
    atomicAdd(&cnt[d >> 10], 1);
  }
  __syncthreads();
  if (tid == 0) {
    int s = 0;
    for (int p = 0; p < NP; ++p) { scn[p] = s; s += cnt[p]; }
  }
  __syncthreads();
  if (tid < NP) {
    base[tid] = (cnt[tid] > 0) ? atomicAdd(&gCursor[tid], cnt[tid]) : 0;
    cur[tid] = 0;
  }
  __syncthreads();
  for (int i = tid; i < ecnt; i += 256) {
    int d = edge_at(edges, f, NE + e0 + i);
    int s = edge_at(edges, f, e0 + i);
    int p = d >> 10;
    int lp = atomicAdd(&cur[p], 1);
    items[scn[p] + lp] = (s << 10) | (d & (PSZ - 1));
  }
  __syncthreads();
  for (int p = 0; p < NP; ++p) {
    int c = cnt[p];
    if (c == 0) continue;
    int gb = base[p];
    int* dst = staging + (size_t)p * PCAP;
    for (int i = tid; i < c; i += 256) {
      int gpos = gb + i;
      if (gpos < PCAP) dst[gpos] = items[scn[p] + i];
    }
  }
}

// ---------------- K1 body B: GEMM1 (r10 double-buffered, proven) ------------
__device__ void gemm1_body(int bid, ushort* smem, const float* x,
                           const ushort* Wth, const ushort* Wtl,
                           ushort* h1b) {
  ushort* sOut = smem;
  const int tid = threadIdx.x;
  const int lane = tid & 63, wid = tid >> 6;
  const int wr = wid >> 1, wc = wid & 1;
  const int lrow = lane & 15, lkg = lane >> 4;
  const int row0 = bid * 128;

  f32x4 acc[4][4];
#pragma unroll
  for (int m = 0; m < 4; ++m)
#pragma unroll
    for (int n = 0; n < 4; ++n) acc[m][n] = (f32x4){0.f, 0.f, 0.f, 0.f};

  float4 ra[4];
  uint4 rbh[2], rbl[2];

#pragma unroll
  for (int i = 0; i < 4; ++i) {
    int flat = i * 256 + tid, r = flat >> 3, kq = flat & 7;
    int grow = row0 + r; if (grow > NN - 1) grow = NN - 1;
    ra[i] = *(const float4*)(x + (size_t)grow * IND + kq * 4);
  }
#pragma unroll
  for (int i = 0; i < 2; ++i) {
    int flat = i * 256 + tid, col = flat >> 2, kc = flat & 3;
    rbh[i] = *(const uint4*)(Wth + (size_t)col * IND + kc * 8);
    rbl[i] = *(const uint4*)(Wtl + (size_t)col * IND + kc * 8);
  }
  {
    ushort* dAh = smem;
    ushort* dBh = smem + 5120;
    ushort* dBl = smem + 10240;
#pragma unroll
    for (int i = 0; i < 4; ++i) {
      int flat = i * 256 + tid, r = flat >> 3, kq = flat & 7;
      ushort4 hi;
      hi.x = f2bf_n(ra[i].x); hi.y = f2bf_n(ra[i].y);
      hi.z = f2bf_n(ra[i].z); hi.w = f2bf_n(ra[i].w);
      *(ushort4*)&dAh[r * 40 + kq * 4] = hi;
    }
#pragma unroll
    for (int i = 0; i < 2; ++i) {
      int flat = i * 256 + tid, col = flat >> 2, kc = flat & 3;
      *(uint4*)&dBh[col * 40 + kc * 8] = rbh[i];
      *(uint4*)&dBl[col * 40 + kc * 8] = rbl[i];
    }
  }

  int cur = 0;
  for (int s = 0; s < 16; ++s) {
    __syncthreads();
    if (s < 15) {
      int kt = (s + 1) * 32;
#pragma unroll
      for (int i = 0; i < 4; ++i) {
        int flat = i * 256 + tid, r = flat >> 3, kq = flat & 7;
        int grow = row0 + r; if (grow > NN - 1) grow = NN - 1;
        ra[i] = *(const float4*)(x + (size_t)grow * IND + kt + kq * 4);
      }
#pragma unroll
      for (int i = 0; i < 2; ++i) {
        int flat = i * 256 + tid, col = flat >> 2, kc = flat & 3;
        rbh[i] = *(const uint4*)(Wth + (size_t)col * IND + kt + kc * 8);
        rbl[i] = *(const uint4*)(Wtl + (size_t)col * IND + kt + kc * 8);
      }
    }
    {
      const ushort* bAh = smem + cur * 15360;
      const ushort* bBh = bAh + 5120;
      const ushort* bBl = bAh + 10240;
      short8v ah[4], bh[4], bl[4];
#pragma unroll
      for (int m = 0; m < 4; ++m) {
        int r = wr * 64 + m * 16 + lrow;
        ah[m] = *(const short8v*)&bAh[r * 40 + lkg * 8];
      }
#pragma unroll
      for (int n = 0; n < 4; ++n) {
        int c = wc * 64 + n * 16 + lrow;
        bh[n] = *(const short8v*)&bBh[c * 40 + lkg * 8];
        bl[n] = *(const short8v*)&bBl[c * 40 + lkg * 8];
      }
#pragma unroll
      for (int m = 0; m < 4; ++m)
#pragma unroll
        for (int n = 0; n < 4; ++n) {
          acc[m][n] = __builtin_amdgcn_mfma_f32_16x16x32_bf16(ah[m], bh[n], acc[m][n], 0, 0, 0);
          acc[m][n] = __builtin_amdgcn_mfma_f32_16x16x32_bf16(ah[m], bl[n], acc[m][n], 0, 0, 0);
        }
    }
    if (s < 15) {
      ushort* dAh = smem + (cur ^ 1) * 15360;
      ushort* dBh = dAh + 5120;
      ushort* dBl = dAh + 10240;
#pragma unroll
      for (int i = 0; i < 4; ++i) {
        int flat = i * 256 + tid, r = flat >> 3, kq = flat & 7;
        ushort4 hi;
        hi.x = f2bf_n(ra[i].x); hi.y = f2bf_n(ra[i].y);
        hi.z = f2bf_n(ra[i].z); hi.w = f2bf_n(ra[i].w);
        *(ushort4*)&dAh[r * 40 + kq * 4] = hi;
      }
#pragma unroll
      for (int i = 0; i < 2; ++i) {
        int flat = i * 256 + tid, col = flat >> 2, kc = flat & 3;
        *(uint4*)&dBh[col * 40 + kc * 8] = rbh[i];
        *(uint4*)&dBl[col * 40 + kc * 8] = rbl[i];
      }
    }
    cur ^= 1;
  }

  __syncthreads();
#pragma unroll
  for (int m = 0; m < 4; ++m)
#pragma unroll
    for (int i = 0; i < 4; ++i) {
      int lr = wr * 64 + m * 16 + lkg * 4 + i;
#pragma unroll
      for (int n = 0; n < 4; ++n)
        sOut[lr * 136 + wc * 64 + n * 16 + lrow] = f2bf_n(acc[m][n][i]);
    }
  __syncthreads();
#pragma unroll
  for (int j = 0; j < 8; ++j) {
    int flat = j * 256 + tid;
    int r = flat >> 4, c = flat & 15;
    int grow = row0 + r;
    if (grow < NN)
      *(uint4*)(h1b + (size_t)grow * HID + c * 8) =
          *(const uint4*)&sOut[r * 136 + c * 8];
  }
}

// ---------------- K1: fused bin (first) + gemm1 -----------------------------
__global__ __launch_bounds__(256) void k_fused1(const float* __restrict__ x,
                                                const ushort* __restrict__ Wth,
                                                const ushort* __restrict__ Wtl,
                                                const int* __restrict__ edges,
                                                const int* __restrict__ flag,
                                                int* __restrict__ gCursor,
                                                int* __restrict__ staging,
                                                ushort* __restrict__ h1b) {
  __shared__ __align__(16) ushort smem[30720];
  if (blockIdx.x < NBIN)
    bin_body(blockIdx.x, smem, edges, flag, gCursor, staging);
  else
    gemm1_body(blockIdx.x - NBIN, smem, x, Wth, Wtl, h1b);
}

// ---------------- CSR pass 2: per-partition counting sort (self-scanned) ----
__global__ __launch_bounds__(256) void k_csrpart(const int* __restrict__ staging,
                                                 const int* __restrict__ gCursor,
                                                 int* __restrict__ offsets,
                                                 int* __restrict__ csr_src) {
  __shared__ int cnt[PSZ];
  __shared__ int cur[PSZ];
  __shared__ int tsum[256];
  __shared__ int srcbuf[PCAP];   // 80 KB
  __shared__ int gbase_s;
  const int tid = threadIdx.x;
  const int p = blockIdx.x;
  // self-compute partition base (fused former k_partscan)
  if (tid == 0) {
    int s = 0;
    for (int q = 0; q < p; ++q) s += min(gCursor[q], PCAP);
    gbase_s = s;
    if (p == NP - 1) offsets[NN] = NE;
  }
  const int tot = min(gCursor[p], PCAP);
  const int* st = staging + (size_t)p * PCAP;
  for (int i = tid; i < PSZ; i += 256) { cnt[i] = 0; cur[i] = 0; }
  __syncthreads();
  const int gbase = gbase_s;
  for (int i = tid; i < tot; i += 256) atomicAdd(&cnt[st[i] & (PSZ - 1)], 1);
  __syncthreads();
  int b0 = tid * 4;
  int c0 = cnt[b0], c1 = cnt[b0 + 1], c2 = cnt[b0 + 2], c3 = cnt[b0 + 3];
  int ls = c0 + c1 + c2 + c3;
  tsum[tid] = ls;
  __syncthreads();
  for (int off = 1; off < 256; off <<= 1) {
    int t = (tid >= off) ? tsum[tid - off] : 0;
    __syncthreads();
    tsum[tid] += t;
    __syncthreads();
  }
  int ebase = tsum[tid] - ls;
  cnt[b0] = ebase;
  cnt[b0 + 1] = ebase + c0;
  cnt[b0 + 2] = ebase + c0 + c1;
  cnt[b0 + 3] = ebase + c0 + c1 + c2;
  __syncthreads();
  for (int i = tid; i < PSZ; i += 256) {
    int node = p * PSZ + i;
    if (node < NN) offsets[node] = gbase + cnt[i];
  }
  for (int i = tid; i < tot; i += 256) {
    int item = st[i];
    int dl = item & (PSZ - 1);
    int lp = atomicAdd(&cur[dl], 1);
    srcbuf[cnt[dl] + lp] = item >> 10;
  }
  __syncthreads();
  for (int i = tid; i < tot; i += 256) csr_src[gbase + i] = srcbuf[i];
}

// ---------------- Aggregation 1 (+b1): aggb[n] = bf16(sum h1[src] + b1) ----
// 2 edges per wave-instruction: lanes 0-31 take even CSR slots, 32-63 odd;
// each lane loads uint2 (4 channels). Halves combined via shfl_xor(32).
__global__ __launch_bounds__(256) void k_agg1(const ushort* __restrict__ h1b,
                                              const int* __restrict__ offsets,
                                              const int* __restrict__ csr_src,
                                              const float* __restrict__ b1,
                                              ushort* __restrict__ aggb) {
  int w = threadIdx.x >> 6, lane = threadIdx.x & 63;
  int n = blockIdx.x * 4 + w;
  if (n >= NN) return;
  int beg = offsets[n], end = offsets[n + 1];
  int half = lane >> 5, ch = lane & 31;
  const uint2* h = (const uint2*)h1b;  // 32 uint2 per row (128 bf16)
  float4 a = {0.f, 0.f, 0.f, 0.f}, a2 = {0.f, 0.f, 0.f, 0.f};
  int i = beg + half;
  for (; i + 2 < end; i += 4) {
    uint2 v0 = h[(size_t)csr_src[i] * 32 + ch];
    uint2 v1 = h[(size_t)csr_src[i + 2] * 32 + ch];
    a.x += bflo(v0.x); a.y += bfhi(v0.x); a.z += bflo(v0.y); a.w += bfhi(v0.y);
    a2.x += bflo(v1.x); a2.y += bfhi(v1.x); a2.z += bflo(v1.y); a2.w += bfhi(v1.y);
  }
  if (i < end) {
    uint2 v = h[(size_t)csr_src[i] * 32 + ch];
    a.x += bflo(v.x); a.y += bfhi(v.x); a.z += bflo(v.y); a.w += bfhi(v.y);
  }
  a.x += a2.x; a.y += a2.y; a.z += a2.z; a.w += a2.w;
  a.x += __shfl_xor(a.x, 32);
  a.y += __shfl_xor(a.y, 32);
  a.z += __shfl_xor(a.z, 32);
  a.w += __shfl_xor(a.w, 32);
  if (half == 0) {
    float4 b = *(const float4*)(b1 + 4 * ch);
    uint2 o;
    o.x = packbf(a.x + b.x, a.y + b.y);
    o.y = packbf(a.z + b.z, a.w + b.w);
    ((uint2*)aggb)[(size_t)n * 32 + ch] = o;
  }
}

// ---------------- BN stats (bf16 input) ------------------------------------
__global__ __launch_bounds__(256) void k_bnstats(const ushort* __restrict__ aggb,
                                                 float* __restrict__ gsum,
                                                 float* __restrict__ gsq) {
  __shared__ float2 ss[4][64], qq[4][64];
  int tid = threadIdx.x;
  int lane = tid & 63, g = tid >> 6;
  int r0 = blockIdx.x * 128;
  const uint* a = (const uint*)aggb;
  float2 s = {0.f, 0.f}, q = {0.f, 0.f};
  for (int k = 0; k < 32; ++k) {
    int r = r0 + g + 4 * k;
    if (r < NN) {
      uint v = a[(size_t)r * 64 + lane];
      float lo = bflo(v), hi = bfhi(v);
      s.x += lo; s.y += hi;
      q.x += lo * lo; q.y += hi * hi;
    }
  }
  ss[g][lane] = s; qq[g][lane] = q;
  __syncthreads();
  if (g == 0) {
    float2 S = ss[0][lane], Q = qq[0][lane];
#pragma unroll
    for (int gg = 1; gg < 4; ++gg) {
      S.x += ss[gg][lane].x; S.y += ss[gg][lane].y;
      Q.x += qq[gg][lane].x; Q.y += qq[gg][lane].y;
    }
    atomicAdd(&gsum[2 * lane], S.x);
    atomicAdd(&gsum[2 * lane + 1], S.y);
    atomicAdd(&gsq[2 * lane], Q.x);
    atomicAdd(&gsq[2 * lane + 1], Q.y);
  }
}

// ---------------- GEMM2 via MFMA (BN-finalize fused in-block) ---------------
__global__ __launch_bounds__(256) void k_gemm2m(const ushort* __restrict__ aggb,
                                                const ushort* __restrict__ W2th,
                                                const ushort* __restrict__ W2tl,
                                                const float* __restrict__ gsum,
                                                const float* __restrict__ gsq,
                                                const float* __restrict__ gamma,
                                                const float* __restrict__ beta,
                                                ushort* __restrict__ h2b) {
  __shared__ __align__(16) ushort smem[27648]; // Bh 8704 | Bl 8704 | Adbuf 10240
  __shared__ float isgS[128], bbS[128];
  ushort* sBh = smem;            // [64][136]
  ushort* sBl = smem + 8704;     // [64][136]
  ushort* sA  = smem + 17408;    // 2 x [128][40]
  ushort* sOut = sA;             // epilogue alias: [128][72]
  const int tid = threadIdx.x;
  const int lane = tid & 63, wid = tid >> 6;
  const int wr = wid >> 1, wc = wid & 1;
  const int lrow = lane & 15, lkg = lane >> 4;
  const int row0 = blockIdx.x * 128;

  if (tid < 128) {  // fused bnfin (redundant per block, trivial)
    float mean = gsum[tid] * (1.f / NN);
    float var = fmaxf(gsq[tid] * (1.f / NN) - mean * mean, 0.f);
    float inv = 1.f / sqrtf(var + BN_EPS);
    float g = gamma[tid] * inv;
    isgS[tid] = g;
    bbS[tid] = beta[tid] - mean * g;
  }
#pragma unroll
  for (int i = 0; i < 4; ++i) {
    int c = i * 256 + tid;
    int n = c >> 4, kq = c & 15;
    *(uint4*)&sBh[n * 136 + kq * 8] = *(const uint4*)(W2th + (size_t)n * HID + kq * 8);
    *(uint4*)&sBl[n * 136 + kq * 8] = *(const uint4*)(W2tl + (size_t)n * HID + kq * 8);
  }

  f32x4 acc[4][2];
#pragma unroll
  for (int m = 0; m < 4; ++m)
#pragma unroll
    for (int n = 0; n < 2; ++n) acc[m][n] = (f32x4){0.f, 0.f, 0.f, 0.f};

  uint4 rA[2];
#pragma unroll
  for (int i = 0; i < 2; ++i) {
    int c = i * 256 + tid;
    int r = c >> 2, cq = c & 3;
    int grow = row0 + r; if (grow > NN - 1) grow = NN - 1;
    rA[i] = *(const uint4*)(aggb + (size_t)grow * HID + cq * 8);
  }
  __syncthreads();  // isgS/bbS + B visible

  {
    ushort* dA = sA;
#pragma unroll
    for (int i = 0; i < 2; ++i) {
      int c = i * 256 + tid;
      int r = c >> 2, cq = c & 3;
      int k0 = cq * 8;
      uint4 v = rA[i];
      uint o[4];
      const uint* vv = (const uint*)&v;
#pragma unroll
      for (int j = 0; j < 4; ++j) {
        float lo = bflo(vv[j]), hi = bfhi(vv[j]);
        lo = fmaxf(fmaf(lo, isgS[k0 + 2 * j], bbS[k0 + 2 * j]), 0.f);
        hi = fmaxf(fmaf(hi, isgS[k0 + 2 * j + 1], bbS[k0 + 2 * j + 1]), 0.f);
        o[j] = packbf(lo, hi);
      }
      *(uint4*)&dA[r * 40 + cq * 8] = *(const uint4*)o;
    }
  }

  int cur = 0;
  for (int s = 0; s < 4; ++s) {
    __syncthreads();
    const int kt = s * 32;
    if (s < 3) {
      int ktn = kt + 32;
#pragma unroll
      for (int i = 0; i < 2; ++i) {
        int c = i * 256 + tid;
        int r = c >> 2, cq = c & 3;
        int grow = row0 + r; if (grow > NN - 1) grow = NN - 1;
        rA[i] = *(const uint4*)(aggb + (size_t)grow * HID + ktn + cq * 8);
      }
    }
    {
      const ushort* bA = sA + cur * 5120;
      short8v ah[4], bh[2], bl[2];
#pragma unroll
      for (int m = 0; m < 4; ++m) {
        int r = wr * 64 + m * 16 + lrow;
        ah[m] = *(const short8v*)&bA[r * 40 + lkg * 8];
      }
#pragma unroll
      for (int n = 0; n < 2; ++n) {
        int c = wc * 32 + n * 16 + lrow;
        bh[n] = *(const short8v*)&sBh[c * 136 + kt + lkg * 8];
        bl[n] = *(const short8v*)&sBl[c * 136 + kt + lkg * 8];
      }
#pragma unroll
      for (int m = 0; m < 4; ++m)
#pragma unroll
        for (int n = 0; n < 2; ++n) {
          acc[m][n] = __builtin_amdgcn_mfma_f32_16x16x32_bf16(ah[m], bh[n], acc[m][n], 0, 0, 0);
          acc[m][n] = __builtin_amdgcn_mfma_f32_16x16x32_bf16(ah[m], bl[n], acc[m][n], 0, 0, 0);
        }
    }
    if (s < 3) {
      ushort* dA = sA + (cur ^ 1) * 5120;
      int k0b = (s + 1) * 32;
#pragma unroll
      for (int i = 0; i < 2; ++i) {
        int c = i * 256 + tid;
        int r = c >> 2, cq = c & 3;
        int k0 = k0b + cq * 8;
        uint4 v = rA[i];
        uint o[4];
        const uint* vv = (const uint*)&v;
#pragma unroll
        for (int j = 0; j < 4; ++j) {
          float lo = bflo(vv[j]), hi = bfhi(vv[j]);
          lo = fmaxf(fmaf(lo, isgS[k0 + 2 * j], bbS[k0 + 2 * j]), 0.f);
          hi = fmaxf(fmaf(hi, isgS[k0 + 2 * j + 1], bbS[k0 + 2 * j + 1]), 0.f);
          o[j] = packbf(lo, hi);
        }
        *(uint4*)&dA[r * 40 + cq * 8] = *(const uint4*)o;
      }
    }
    cur ^= 1;
  }

  __syncthreads();
#pragma unroll
  for (int m = 0; m < 4; ++m)
#pragma unroll
    for (int i = 0; i < 4; ++i) {
      int lr = wr * 64 + m * 16 + lkg * 4 + i;
#pragma unroll
      for (int n = 0; n < 2; ++n)
        sOut[lr * 72 + wc * 32 + n * 16 + lrow] = f2bf_n(acc[m][n][i]);
    }
  __syncthreads();
#pragma unroll
  for (int i = 0; i < 4; ++i) {
    int c = i * 256 + tid;
    int r = c >> 3, cq = c & 7;
    int grow = row0 + r;
    if (grow < NN)
      *(uint4*)(h2b + (size_t)grow * OUTD + cq * 8) =
          *(const uint4*)&sOut[r * 72 + cq * 8];
  }
}

// ---------------- Aggregation 2 + b2 + L2 normalize + fp32 store -----------
// 2 edges per wave-instruction (halves), uint loads (2 channels/lane).
__global__ __launch_bounds__(256) void k_agg2norm(const ushort* __restrict__ h2b,
                                                  const int* __restrict__ offsets,
                                                  const int* __restrict__ csr_src,
                                                  const float* __restrict__ b2,
                                                  float* __restrict__ out) {
  int w = threadIdx.x >> 6, lane = threadIdx.x & 63;
  int n = blockIdx.x * 4 + w;
  if (n >= NN) return;
  int beg = offsets[n], end = offsets[n + 1];
  int half = lane >> 5, ch = lane & 31;
  const uint* h = (const uint*)h2b;  // 32 uints per row (64 bf16)
  float2 a = {0.f, 0.f}, a2 = {0.f, 0.f};
  int i = beg + half;
  for (; i + 2 < end; i += 4) {
    uint v0 = h[(size_t)csr_src[i] * 32 + ch];
    uint v1 = h[(size_t)csr_src[i + 2] * 32 + ch];
    a.x += bflo(v0); a.y += bfhi(v0);
    a2.x += bflo(v1); a2.y += bfhi(v1);
  }
  if (i < end) {
    uint v = h[(size_t)csr_src[i] * 32 + ch];
    a.x += bflo(v); a.y += bfhi(v);
  }
  a.x += a2.x; a.y += a2.y;
  a.x += __shfl_xor(a.x, 32);
  a.y += __shfl_xor(a.y, 32);
  float2 b = *(const float2*)(b2 + 2 * ch);
  a.x += b.x; a.y += b.y;
  float q = a.x * a.x + a.y * a.y;
#pragma unroll
  for (int off = 16; off > 0; off >>= 1) q += __shfl_xor(q, off);
  float norm = sqrtf(q);
  float scale = 1.f / fmaxf(norm, 1e-12f);
  if (half == 0) {
    float2 o = {a.x * scale, a.y * scale};
    *(float2*)(out + (size_t)n * OUTD + 2 * ch) = o;
  }
}

// ---------------- launch ----------------------------------------------------
extern "C" void kernel_launch(void* const* d_in, const int* in_sizes, int n_in,
                              void* d_out, int out_size, void* d_ws, size_t ws_size,
                              hipStream_t stream) {
  const float* x     = (const float*)d_in[0];
  const int*   edges = (const int*)d_in[1];
  const float* W1    = (const float*)d_in[2];
  const float* b1    = (const float*)d_in[3];
  const float* W2    = (const float*)d_in[4];
  const float* b2    = (const float*)d_in[5];
  const float* gamma = (const float*)d_in[6];
  const float* beta  = (const float*)d_in[7];

  char* ws = (char*)d_ws;
  ushort* h1b     = (ushort*)(ws);                // 25.6 MB
  ushort* aggb    = (ushort*)(ws + 26000000);     // 25.6 MB (bf16)
  int*    csr_src = (int*)(ws + 77500000);        // 6.4 MB
  int*    offsets = (int*)(ws + 84000000);        // 100001 ints
  int*    staging = (int*)(ws + 84400128);        // 98*20480*4 = 8,028,160 B
  int*    gCursor = (int*)(ws + 92428544);        // 98 ints (512B region)
  int*    partBase= (int*)(ws + 92429056);        // unused (kept for layout)
  float*  gsum    = (float*)(ws + 92429568);      // 128 f
  float*  gsq     = (float*)(ws + 92430080);      // 128 f
  int*    eflag   = (int*)(ws + 92431616);        // 1 int
  ushort* Wth     = (ushort*)(ws + 92432128);     // 128 KB
  ushort* Wtl     = (ushort*)(ws + 92563200);     // 128 KB
  ushort* W2th    = (ushort*)(ws + 92694272);     // 16 KB
  ushort* W2tl    = (ushort*)(ws + 92710656);     // 16 KB
  ushort* h2b     = h1b;                          // reuse (h1b dead after agg1)
  (void)partBase;

  if (ws_size < 92727040) return;  // scratch layout requirement

  // zero gCursor + partBase + gsum + gsq (2 KB)
  hipMemsetAsync(gCursor, 0, 2048, stream);

  k_prep<<<289, 256, 0, stream>>>(edges, W1, W2, eflag, Wth, Wtl, W2th, W2tl);
  k_fused1<<<NBIN + 782, 256, 0, stream>>>(x, Wth, Wtl, edges, eflag,
                                           gCursor, staging, h1b);
  k_csrpart<<<NP, 256, 0, stream>>>(staging, gCursor, offsets, csr_src);
  k_agg1<<<25000, 256, 0, stream>>>(h1b, offsets, csr_src, b1, aggb);
  k_bnstats<<<782, 256, 0, stream>>>(aggb, gsum, gsq);
  k_gemm2m<<<782, 256, 0, stream>>>(aggb, W2th, W2tl, gsum, gsq, gamma, beta, h2b);
  k_agg2norm<<<25000, 256, 0, stream>>>(h2b, offsets, csr_src, b2,
                                        (float*)d_out);
}